// Round 4
// baseline (335.863 us; speedup 1.0000x reference)
//
#include <hip/hip_runtime.h>
#include <hip/hip_fp16.h>

// ---------------------------------------------------------------------------
// GATv2 x2 + classifier. N=50000, E=800000, IN=128, HEADS=4, HID=32, OUT=16.
// R14: classifier fusion kept but LDS Wc dropped -- R13 counters showed
//      SQ_LDS_BANK_CONFLICT=11.2M (= +18us on attn2): a [128][16] row-major
//      W is bank-degenerate for l15-strided row reads (l15 stride 512B == 0
//      mod 128B -> 16-way). Each lane now loads its 32 Wc floats (8xfloat4)
//      directly from global at the classifier point: Wc is 8KB -> L1-resident
//      per CU, conflict-free, no syncthreads, LDS 8192->0.
//      Kept from R12/R13: fused scatter+gemm1 with slice<->XCD static binding
//      (clean csr writes), 4x-batched scatter scan, plain (non-NT) loads,
//      4-edge attn ILP body, fma_mix attn math, h1 fp16, setprio MFMA.
// ---------------------------------------------------------------------------

#define LOG2E 1.4426950408889634f
#define AST 40  // LDS row stride in shorts (80B rows; fragment reads 2-way=free)

typedef short bf16x8 __attribute__((ext_vector_type(8)));
typedef float f32x4 __attribute__((ext_vector_type(4)));

__device__ __forceinline__ unsigned short f2bf(float f) {
  union { float f; unsigned u; } x; x.f = f;
  unsigned r = x.u + 0x7fffu + ((x.u >> 16) & 1u);
  return (unsigned short)(r >> 16);
}
__device__ __forceinline__ float bf2f(unsigned short h) {
  union { unsigned u; float f; } x; x.u = ((unsigned)h) << 16;
  return x.f;
}
__device__ __forceinline__ void split4(float4 v, ushort4& h, ushort4& l) {
  h.x = f2bf(v.x); l.x = f2bf(v.x - bf2f(h.x));
  h.y = f2bf(v.y); l.y = f2bf(v.y - bf2f(h.y));
  h.z = f2bf(v.z); l.z = f2bf(v.z - bf2f(h.z));
  h.w = f2bf(v.w); l.w = f2bf(v.w - bf2f(h.w));
}

// ---- v_fma_mix_f32 helpers: d = a * (f16 half of b) + c, all-f32 accum ----
__device__ __forceinline__ float mixlo(float a, unsigned b, float c) {
  float d;
  asm("v_fma_mix_f32 %0, %1, %2, %3 op_sel_hi:[0,1,0]"
      : "=v"(d) : "v"(a), "v"(b), "v"(c));
  return d;
}
__device__ __forceinline__ float mixhi(float a, unsigned b, float c) {
  float d;
  asm("v_fma_mix_f32 %0, %1, %2, %3 op_sel:[0,1,0] op_sel_hi:[0,1,0]"
      : "=v"(d) : "v"(a), "v"(b), "v"(c));
  return d;
}
__device__ __forceinline__ float mixlo_abs(float a, unsigned b, float c) {
  float d;
  asm("v_fma_mix_f32 %0, %1, |%2|, %3 op_sel_hi:[0,1,0]"
      : "=v"(d) : "v"(a), "v"(b), "v"(c));
  return d;
}
__device__ __forceinline__ float mixhi_abs(float a, unsigned b, float c) {
  float d;
  asm("v_fma_mix_f32 %0, %1, |%2|, %3 op_sel:[0,1,0] op_sel_hi:[0,1,0]"
      : "=v"(d) : "v"(a), "v"(b), "v"(c));
  return d;
}
__device__ __forceinline__ unsigned pk_add(unsigned a, unsigned b) {
  union { unsigned u; __half2 h; } x, y, r;
  x.u = a; y.u = b;
  r.h = __hadd2(x.h, y.h);
  return r.u;
}

// e = sum_k a06[k]*t + a04[k]*|t| over 8 fp16 channels (t = xl+xr)
__device__ __forceinline__ float edot(uint4 raw, const unsigned* hxr,
                                      const float* a06, const float* a04) {
  const unsigned* xp = (const unsigned*)&raw;
  float ea = 0.f, eb = 0.f;
#pragma unroll
  for (int j = 0; j < 4; ++j) {
    unsigned tw = pk_add(xp[j], hxr[j]);
    ea = mixlo(a06[2 * j], tw, ea);
    ea = mixlo_abs(a04[2 * j], tw, ea);
    eb = mixhi(a06[2 * j + 1], tw, eb);
    eb = mixhi_abs(a04[2 * j + 1], tw, eb);
  }
  return ea + eb;
}
__device__ __forceinline__ void accupd(float p, uint4 raw, float* acc) {
  const unsigned* xp = (const unsigned*)&raw;
#pragma unroll
  for (int j = 0; j < 4; ++j) {
    acc[2 * j] = mixlo(p, xp[j], acc[2 * j]);
    acc[2 * j + 1] = mixhi(p, xp[j], acc[2 * j + 1]);
  }
}

// ------------------------------ CSR build ----------------------------------

__global__ __launch_bounds__(256) void zero_i32(int* __restrict__ p, int n) {
  int i = blockIdx.x * 256 + threadIdx.x;
  if (i < n) p[i] = 0;
}

// per-block scan of (cnt[i]+1)  (+1 = self loop slot)
__global__ __launch_bounds__(256) void scan_blk(const int* __restrict__ cnt,
                                                int* __restrict__ excl,
                                                int* __restrict__ bsum, int n) {
  __shared__ int s[256];
  int t = threadIdx.x, i = blockIdx.x * 256 + t;
  int v = (i < n) ? (cnt[i] + 1) : 0;
  s[t] = v;
  __syncthreads();
#pragma unroll
  for (int off = 1; off < 256; off <<= 1) {
    int u = (t >= off) ? s[t - off] : 0;
    __syncthreads();
    s[t] += u;
    __syncthreads();
  }
  if (i < n) excl[i] = s[t] - v;
  if (t == 255) bsum[blockIdx.x] = s[255];
}

__global__ __launch_bounds__(256) void scan_bsum(int* __restrict__ bsum, int nb,
                                                 int* __restrict__ row_start, int n) {
  __shared__ int s[256];
  int t = threadIdx.x;
  int v = (t < nb) ? bsum[t] : 0;
  s[t] = v;
  __syncthreads();
#pragma unroll
  for (int off = 1; off < 256; off <<= 1) {
    int u = (t >= off) ? s[t - off] : 0;
    __syncthreads();
    s[t] += u;
    __syncthreads();
  }
  if (t < nb) bsum[t] = s[t] - v;
  if (t == 255) row_start[n] = s[255];
}

// add block offsets; write self-loop entry; wpos starts past it; zero csr pad
__global__ __launch_bounds__(256) void scan_add(int* __restrict__ row_start,
                                                const int* __restrict__ bsum,
                                                int* __restrict__ wpos,
                                                int* __restrict__ csr,
                                                int n, int padBase) {
  int i = blockIdx.x * 256 + threadIdx.x;
  if (i < n) {
    int r = row_start[i] + bsum[blockIdx.x];
    row_start[i] = r;
    wpos[i] = r + 1;
    csr[r] = i;  // self loop first in each row
  }
  if (blockIdx.x == 0 && threadIdx.x < 16) csr[padBase + threadIdx.x] = 0;
}

// --------------------- weight convert + degree count -----------------------
// blocks 0..255: split-bf16 weight transpose (both layers)
// blocks 256.. : edge-degree count (independent work, merged launch)
__global__ __launch_bounds__(256) void convert_count(
    const float* __restrict__ Wl1, const float* __restrict__ Wr1,
    const float* __restrict__ Wl2, const float* __restrict__ Wr2,
    unsigned short* __restrict__ BT1h, unsigned short* __restrict__ BT1l,
    unsigned short* __restrict__ BT2h, unsigned short* __restrict__ BT2l,
    const int* __restrict__ dst, int* __restrict__ cnt, int E) {
  int b = blockIdx.x;
  if (b >= 256) {
    int i = (b - 256) * 256 + threadIdx.x;
    if (i < E) atomicAdd(&cnt[dst[i]], 1);
    return;
  }
  const float* Wl = (b < 128) ? Wl1 : Wl2;
  const float* Wr = (b < 128) ? Wr1 : Wr2;
  unsigned short* BTh = (b < 128) ? BT1h : BT2h;
  unsigned short* BTl = (b < 128) ? BT1l : BT2l;
  int idx = (b & 127) * 256 + threadIdx.x;  // 0..32767
  int col = idx >> 7, k = idx & 127;
  float v = (col < 128) ? Wl[k * 128 + col] : Wr[k * 128 + (col - 128)];
  unsigned short h = f2bf(v);
  BTh[idx] = h;
  BTl[idx] = f2bf(v - bf2f(h));
}

// ------------------------ MFMA GEMM (+fused scatter) -----------------------
// C[N x 256] = A[N x 128] @ W[128 x 256], split-bf16 3-term; C stored fp16.
// Block = 128 rows x 128 cols. 4 waves, each 64x64 (16 acc tiles).
// FUSE=1: grid also carries scatter blocks (5 of every 9). Scatter slice is
// the REAL blockIdx&7 (== XCD on round-robin dispatch) so each csr slice is
// written by exactly one XCD's L2; chunk = rank among same-slice blocks.
enum { IN_F32 = 0, IN_F16 = 1 };
#define NSCAT 1152
#define NCHUNK 128
template <int MODE, int FUSE>
__global__ __launch_bounds__(256) void gemm_mfma(
    const float* __restrict__ Af, const __half* __restrict__ Af16,
    const unsigned short* __restrict__ BTh, const unsigned short* __restrict__ BTl,
    __half* __restrict__ Cl, __half* __restrict__ Cr, int nrows,
    const int* __restrict__ esrc, const int* __restrict__ edst,
    int* __restrict__ wpos, int* __restrict__ csr, int E, int sliceSize) {
  __shared__ __align__(16) unsigned short smem[4 * 128 * AST];
  int tid = threadIdx.x;
  int bx, by;
  if (FUSE) {
    int g = blockIdx.x / 9, r = blockIdx.x - g * 9;
    if (r < 5) {  // ---- scatter role ----
      int sid = g * 5 + r;
      if (sid < NSCAT) {
        int slice = blockIdx.x & 7;  // == XCD (round-robin dispatch)
        // rank among scatter blocks with the same slice, ordered by g:
        // block (g',r') has slice (g'+r')&7; per g' at most one r'<5 matches.
        int chunk = (g >> 3) * 5;
        for (int gp = g & ~7; gp < g; ++gp)
          chunk += (((slice - gp) & 7) < 5) ? 1 : 0;
        if (chunk < NCHUNK) {
          int per = (E + NCHUNK - 1) / NCHUNK;
          int b0 = chunk * per;
          int ee = min(b0 + per, E);
          int lo = slice * sliceSize, hi = lo + sliceSize;
          int i = b0 + tid;
          // 4x-batched scan: 4 independent dst loads in flight
          for (; i + 768 < ee; i += 1024) {
            int d0 = edst[i];
            int d1 = edst[i + 256];
            int d2 = edst[i + 512];
            int d3 = edst[i + 768];
            if (d0 >= lo && d0 < hi) {
              int s = esrc[i];
              int p = atomicAdd(&wpos[d0], 1); csr[p] = s;
            }
            if (d1 >= lo && d1 < hi) {
              int s = esrc[i + 256];
              int p = atomicAdd(&wpos[d1], 1); csr[p] = s;
            }
            if (d2 >= lo && d2 < hi) {
              int s = esrc[i + 512];
              int p = atomicAdd(&wpos[d2], 1); csr[p] = s;
            }
            if (d3 >= lo && d3 < hi) {
              int s = esrc[i + 768];
              int p = atomicAdd(&wpos[d3], 1); csr[p] = s;
            }
          }
          for (; i < ee; i += 256) {
            int d = edst[i];
            if (d >= lo && d < hi) {
              int s = esrc[i];
              int p = atomicAdd(&wpos[d], 1); csr[p] = s;
            }
          }
        }
      }
      return;
    }
    int gid = g * 4 + (r - 5);  // ---- gemm role ----
    int nbx = (nrows + 127) >> 7;
    if (gid >= nbx * 2) return;
    bx = gid >> 1;
    by = gid & 1;
  } else {
    bx = blockIdx.x;
    by = blockIdx.y;
  }

  unsigned short* sAh = smem;
  unsigned short* sAl = smem + 5120;
  unsigned short* sBh = smem + 10240;
  unsigned short* sBl = smem + 15360;

  int wave = tid >> 6, lane = tid & 63;
  int rowBase = bx * 128;
  int colBase = by * 128;
  int rowHalf = (wave >> 1) * 64;
  int colHalf = (wave & 1) * 64;
  int l15 = lane & 15, quad = lane >> 4;

  f32x4 acc[4][4];
#pragma unroll
  for (int m = 0; m < 4; ++m)
#pragma unroll
    for (int n = 0; n < 4; ++n) acc[m][n] = (f32x4){0.f, 0.f, 0.f, 0.f};

  for (int kc = 0; kc < 4; ++kc) {
    // stage A: 128 rows x 32 k (hi+lo); idx 0..511, 8 k-elems each
#pragma unroll
    for (int i = 0; i < 2; ++i) {
      int idx = tid + i * 256;
      int row = idx >> 2, seg = idx & 3;
      int gr = rowBase + row;
      float4 v0 = make_float4(0.f, 0.f, 0.f, 0.f), v1 = v0;
      if (MODE == IN_F32) {
        if (gr < nrows) {
          v0 = *(const float4*)&Af[(size_t)gr * 128 + kc * 32 + seg * 8];
          v1 = *(const float4*)&Af[(size_t)gr * 128 + kc * 32 + seg * 8 + 4];
        }
      } else {
        if (gr < nrows) {
          uint4 raw = *(const uint4*)&Af16[(size_t)gr * 128 + kc * 32 + seg * 8];
          const __half* hp = (const __half*)&raw;
          v0 = make_float4(__half2float(hp[0]), __half2float(hp[1]),
                           __half2float(hp[2]), __half2float(hp[3]));
          v1 = make_float4(__half2float(hp[4]), __half2float(hp[5]),
                           __half2float(hp[6]), __half2float(hp[7]));
        }
      }
      ushort4 h0, l0, h1, l1;
      split4(v0, h0, l0);
      split4(v1, h1, l1);
      *(ushort4*)&sAh[row * AST + seg * 8] = h0;
      *(ushort4*)&sAh[row * AST + seg * 8 + 4] = h1;
      *(ushort4*)&sAl[row * AST + seg * 8] = l0;
      *(ushort4*)&sAl[row * AST + seg * 8 + 4] = l1;
    }
    // stage B: 128 cols x 32 k (hi+lo); idx 0..511
#pragma unroll
    for (int i = 0; i < 2; ++i) {
      int idx = tid + i * 256;
      int col = idx >> 2, seg = idx & 3;
      *(uint4*)&sBh[col * AST + seg * 8] =
          *(const uint4*)&BTh[(size_t)(colBase + col) * 128 + kc * 32 + seg * 8];
      *(uint4*)&sBl[col * AST + seg * 8] =
          *(const uint4*)&BTl[(size_t)(colBase + col) * 128 + kc * 32 + seg * 8];
    }
    __syncthreads();

    bf16x8 afh[4], afl[4], bfh[4], bfl[4];
#pragma unroll
    for (int m = 0; m < 4; ++m) {
      int r = rowHalf + m * 16 + l15;
      afh[m] = *(const bf16x8*)&sAh[r * AST + quad * 8];
      afl[m] = *(const bf16x8*)&sAl[r * AST + quad * 8];
    }
#pragma unroll
    for (int n = 0; n < 4; ++n) {
      int cc = colHalf + n * 16 + l15;
      bfh[n] = *(const bf16x8*)&sBh[cc * AST + quad * 8];
      bfl[n] = *(const bf16x8*)&sBl[cc * AST + quad * 8];
    }
    __builtin_amdgcn_s_setprio(1);
#pragma unroll
    for (int m = 0; m < 4; ++m)
#pragma unroll
      for (int n = 0; n < 4; ++n) {
        acc[m][n] = __builtin_amdgcn_mfma_f32_16x16x32_bf16(afh[m], bfh[n], acc[m][n], 0, 0, 0);
        acc[m][n] = __builtin_amdgcn_mfma_f32_16x16x32_bf16(afh[m], bfl[n], acc[m][n], 0, 0, 0);
        acc[m][n] = __builtin_amdgcn_mfma_f32_16x16x32_bf16(afl[m], bfh[n], acc[m][n], 0, 0, 0);
      }
    __builtin_amdgcn_s_setprio(0);
    __syncthreads();
  }

  __half* __restrict__ C = (by == 0) ? Cl : Cr;
#pragma unroll
  for (int m = 0; m < 4; ++m)
#pragma unroll
    for (int r = 0; r < 4; ++r) {
      int grow = rowBase + rowHalf + m * 16 + quad * 4 + r;
      if (grow < nrows) {
#pragma unroll
        for (int n = 0; n < 4; ++n)
          C[(size_t)grow * 128 + colHalf + n * 16 + l15] = __float2half(acc[m][n][r]);
      }
    }
}

// ------------------------------ attention ----------------------------------
// One wave per node; 16 lanes/edge (8 ch/lane, one b128 fp16 load);
// 4 edge-slots/wave, 4-edge batched ILP body. Inner math: v_pk_add_f16 +
// v_fma_mix_f32. Outputs fp32 and/or fp16; optional fused classifier
// (logits != nullptr): per-lane Wc from global (8KB, L1-resident), 4
// partials/lane, 16-lane butterfly. No LDS.
__global__ __launch_bounds__(256) void gat_attn(const __half* __restrict__ xl,
                                                const __half* __restrict__ xr,
                                                const int* __restrict__ row_start,
                                                const int* __restrict__ csr,
                                                const float* __restrict__ att,
                                                const float* __restrict__ bias,
                                                float* __restrict__ ofp,
                                                __half* __restrict__ oh16,
                                                const float* __restrict__ Wc,
                                                const float* __restrict__ bc,
                                                float* __restrict__ logits,
                                                int n_nodes) {
  int tid = threadIdx.x;
  int node = blockIdx.x * 4 + (tid >> 6);
  if (node >= n_nodes) return;
  int lane = tid & 63;
  int slot = lane >> 4;
  int l15 = lane & 15;
  int c0 = l15 * 8;

  // xr row kept packed fp16 (4 half2 words)
  unsigned hxr[4];
  {
    uint4 raw = *(const uint4*)&xr[(size_t)node * 128 + c0];
    const unsigned* q = (const unsigned*)&raw;
    hxr[0] = q[0]; hxr[1] = q[1]; hxr[2] = q[2]; hxr[3] = q[3];
  }
  // att row, pre-scaled: a06 = 0.6*log2e*a, a04 = 0.4*log2e*a
  float a06[8], a04[8];
  {
    float4 a0 = *(const float4*)&att[c0];
    float4 a1 = *(const float4*)&att[c0 + 4];
    float av[8] = {a0.x, a0.y, a0.z, a0.w, a1.x, a1.y, a1.z, a1.w};
    const float C06 = 0.6f * LOG2E, C04 = 0.4f * LOG2E;
#pragma unroll
    for (int k = 0; k < 8; ++k) { a06[k] = av[k] * C06; a04[k] = av[k] * C04; }
  }

  float acc[8];
#pragma unroll
  for (int k = 0; k < 8; ++k) acc[k] = 0.f;
  float lsum = 0.f;

  int beg = row_start[node], end = row_start[node + 1];
  int deg = end - beg;  // includes self
  int fullEnd = beg + (deg & ~15);

  for (int base = beg; base < fullEnd; base += 16) {
    int b0 = base + 4 * slot;
    int s0 = csr[b0];
    int s1 = csr[b0 + 1];
    int s2 = csr[b0 + 2];
    int s3 = csr[b0 + 3];
    uint4 r0 = *(const uint4*)&xl[(size_t)(unsigned)s0 * 128 + c0];
    uint4 r1 = *(const uint4*)&xl[(size_t)(unsigned)s1 * 128 + c0];
    uint4 r2 = *(const uint4*)&xl[(size_t)(unsigned)s2 * 128 + c0];
    uint4 r3 = *(const uint4*)&xl[(size_t)(unsigned)s3 * 128 + c0];
    float e0 = edot(r0, hxr, a06, a04);
    float e1 = edot(r1, hxr, a06, a04);
    float e2 = edot(r2, hxr, a06, a04);
    float e3 = edot(r3, hxr, a06, a04);
    e0 += __shfl_xor(e0, 1); e1 += __shfl_xor(e1, 1);
    e2 += __shfl_xor(e2, 1); e3 += __shfl_xor(e3, 1);
    e0 += __shfl_xor(e0, 2); e1 += __shfl_xor(e1, 2);
    e2 += __shfl_xor(e2, 2); e3 += __shfl_xor(e3, 2);
    float p0 = __builtin_amdgcn_exp2f(e0);
    float p1 = __builtin_amdgcn_exp2f(e1);
    float p2 = __builtin_amdgcn_exp2f(e2);
    float p3 = __builtin_amdgcn_exp2f(e3);
    lsum += (p0 + p1) + (p2 + p3);
    accupd(p0, r0, acc);
    accupd(p1, r1, acc);
    accupd(p2, r2, acc);
    accupd(p3, r3, acc);
  }
  for (int base = fullEnd; base < end; base += 4) {  // csr padded by 16
    int idx = base + slot;
    int src = csr[idx];
    uint4 raw = *(const uint4*)&xl[(size_t)(unsigned)src * 128 + c0];
    float e = edot(raw, hxr, a06, a04);
    e += __shfl_xor(e, 1);
    e += __shfl_xor(e, 2);
    float p = (idx < end) ? __builtin_amdgcn_exp2f(e) : 0.f;
    lsum += p;
    accupd(p, raw, acc);
  }

  // fused-classifier weight loads: issue early so L1/L2 latency overlaps the
  // slot-merge shuffle chain. Wc is 8KB -> L1-resident, conflict-free.
  int ob = slot * 4;
  float4 wv[8];
  if (logits) {
#pragma unroll
    for (int k = 0; k < 8; ++k)
      wv[k] = *(const float4*)&Wc[(size_t)(c0 + k) * 16 + ob];
  }

  // merge the 4 slots (same channels live in lanes with equal l15)
  lsum += __shfl_xor(lsum, 16);
  lsum += __shfl_xor(lsum, 32);
#pragma unroll
  for (int k = 0; k < 8; ++k) {
    acc[k] += __shfl_xor(acc[k], 16);
    acc[k] += __shfl_xor(acc[k], 32);
  }

  // all lanes compute o (slots redundant; needed lane-local for classifier)
  float o[8];
  {
    float4 b0v = *(const float4*)&bias[c0];
    float4 b1v = *(const float4*)&bias[c0 + 4];
    float bv[8] = {b0v.x, b0v.y, b0v.z, b0v.w, b1v.x, b1v.y, b1v.z, b1v.w};
    float inv = 1.f / (lsum + 1e-16f);
#pragma unroll
    for (int k = 0; k < 8; ++k) {
      float v = fmaf(acc[k], inv, bv[k]);
      o[k] = fmaf(0.495f, fabsf(v), 0.505f * v);  // leaky 0.01
    }
  }

  if (slot == 0) {
    if (ofp) {
      *(float4*)&ofp[(size_t)node * 128 + c0] = make_float4(o[0], o[1], o[2], o[3]);
      *(float4*)&ofp[(size_t)node * 128 + c0 + 4] = make_float4(o[4], o[5], o[6], o[7]);
    }
    if (oh16) {
      ushort4 ha, hb;
      ha.x = __half_as_ushort(__float2half(o[0]));
      ha.y = __half_as_ushort(__float2half(o[1]));
      ha.z = __half_as_ushort(__float2half(o[2]));
      ha.w = __half_as_ushort(__float2half(o[3]));
      hb.x = __half_as_ushort(__float2half(o[4]));
      hb.y = __half_as_ushort(__float2half(o[5]));
      hb.z = __half_as_ushort(__float2half(o[6]));
      hb.w = __half_as_ushort(__float2half(o[7]));
      *(ushort4*)&oh16[(size_t)node * 128 + c0] = ha;
      *(ushort4*)&oh16[(size_t)node * 128 + c0 + 4] = hb;
    }
  }

  if (logits) {  // fused classifier: outputs ob..ob+3 partial over 8 chans
    float pj0 = 0.f, pj1 = 0.f, pj2 = 0.f, pj3 = 0.f;
#pragma unroll
    for (int k = 0; k < 8; ++k) {
      pj0 = fmaf(o[k], wv[k].x, pj0);
      pj1 = fmaf(o[k], wv[k].y, pj1);
      pj2 = fmaf(o[k], wv[k].z, pj2);
      pj3 = fmaf(o[k], wv[k].w, pj3);
    }
#pragma unroll
    for (int m = 1; m < 16; m <<= 1) {
      pj0 += __shfl_xor(pj0, m);
      pj1 += __shfl_xor(pj1, m);
      pj2 += __shfl_xor(pj2, m);
      pj3 += __shfl_xor(pj3, m);
    }
    if (l15 < 4) {
      float pv = (l15 == 0) ? pj0 : (l15 == 1) ? pj1 : (l15 == 2) ? pj2 : pj3;
      logits[(size_t)node * 16 + ob + l15] = pv + bc[ob + l15];
    }
  }
}

// ---------------------------------------------------------------------------

extern "C" void kernel_launch(void* const* d_in, const int* in_sizes, int n_in,
                              void* d_out, int out_size, void* d_ws, size_t ws_size,
                              hipStream_t stream) {
  const float* x    = (const float*)d_in[0];
  const int*   ei   = (const int*)d_in[1];
  const float* Wl1  = (const float*)d_in[3];
  const float* Wr1  = (const float*)d_in[4];
  const float* att1 = (const float*)d_in[5];
  const float* b1   = (const float*)d_in[6];
  const float* Wl2  = (const float*)d_in[7];
  const float* Wr2  = (const float*)d_in[8];
  const float* att2 = (const float*)d_in[9];
  const float* b2   = (const float*)d_in[10];
  const float* Wc   = (const float*)d_in[11];
  const float* bc   = (const float*)d_in[12];

  const int N = in_sizes[0] / 128;
  const int E = in_sizes[1] / 2;

  float* outp   = (float*)d_out;
  float* logits = outp;                   // N*16 fp32
  float* hout   = outp + (size_t)N * 16;  // N*128 fp32 region
  // h1 (fp16) staged in the hout region (overwritten by fp32 h2 later)
  __half* h1f16 = (__half*)hout;

  char* ws = (char*)d_ws;
  __half* xlbuf = (__half*)ws;                ws += (size_t)N * 128 * 2;
  __half* xrbuf = (__half*)ws;                ws += (size_t)N * 128 * 2;
  unsigned short* WT1h = (unsigned short*)ws; ws += 256 * 128 * 2;
  unsigned short* WT1l = (unsigned short*)ws; ws += 256 * 128 * 2;
  unsigned short* WT2h = (unsigned short*)ws; ws += 256 * 128 * 2;
  unsigned short* WT2l = (unsigned short*)ws; ws += 256 * 128 * 2;
  int* cnt       = (int*)ws;                  ws += (size_t)N * 4;
  int* row_start = (int*)ws;                  ws += (size_t)(N + 1) * 4;
  int* wpos      = (int*)ws;                  ws += (size_t)N * 4;
  int* bsum      = (int*)ws;                  ws += 256 * 4;
  int* csr       = (int*)ws;                  ws += (size_t)(E + N + 16) * 4;

  const int* esrc = ei;
  const int* edst = ei + E;

  int gN = (N + 255) / 256, gE = (E + 255) / 256;
  int gAttn = (N + 3) / 4;
  int sliceSize = (N + 7) / 8;

  int nbx = (N + 127) / 128;
  int nGemm = nbx * 2;
  int groups = (NSCAT + 4) / 5;  // 231 -> covers >=128 chunks per slice
  int g2 = (nGemm + 3) / 4;
  if (g2 > groups) groups = g2;
  int gFused = groups * 9;

  // CSR build (self loops embedded: counts+1, csr[beg]=node)
  zero_i32<<<gN, 256, 0, stream>>>(cnt, N);
  convert_count<<<256 + gE, 256, 0, stream>>>(Wl1, Wr1, Wl2, Wr2,
                                              WT1h, WT1l, WT2h, WT2l,
                                              edst, cnt, E);
  scan_blk<<<gN, 256, 0, stream>>>(cnt, row_start, bsum, N);
  scan_bsum<<<1, 256, 0, stream>>>(bsum, gN, row_start, N);
  scan_add<<<gN, 256, 0, stream>>>(row_start, bsum, wpos, csr, N, E + N);

  // layer 1 GEMM (fp32 x, split inline) fused with CSR scatter
  gemm_mfma<IN_F32, 1><<<gFused, 256, 0, stream>>>(
      x, nullptr, WT1h, WT1l, xlbuf, xrbuf, N,
      esrc, edst, wpos, csr, E, sliceSize);
  gat_attn<<<gAttn, 256, 0, stream>>>(xlbuf, xrbuf, row_start, csr, att1, b1,
                                      nullptr, h1f16, nullptr, nullptr, nullptr, N);

  // layer 2 (reads fp16 h1, splits inline; writes fp16 xl/xr)
  gemm_mfma<IN_F16, 0><<<dim3(nbx, 2), 256, 0, stream>>>(
      nullptr, h1f16, WT2h, WT2l, xlbuf, xrbuf, N,
      nullptr, nullptr, nullptr, nullptr, 0, 0);
  // layer-2 attention with fused classifier
  gat_attn<<<gAttn, 256, 0, stream>>>(xlbuf, xrbuf, row_start, csr, att2, b2,
                                      hout, nullptr, Wc, bc, logits, N);
}

// Round 5
// 329.493 us; speedup vs baseline: 1.0193x; 1.0193x over previous
//
#include <hip/hip_runtime.h>
#include <hip/hip_fp16.h>

// ---------------------------------------------------------------------------
// GATv2 x2 + classifier. N=50000, E=800000, IN=128, HEADS=4, HID=32, OUT=16.
// R15: attn edge loop rebuilt as 2-stage software pipeline. Counters R10->R14
//      showed duration rising (46->68->84us) exactly as VALUBusy fell
//      (56->46->38%) at constant FETCH/WRITE and 18% HBM: gather-latency
//      bound; the fma_mix instruction cut just drained the latency shadow.
//      (a) unified masked tail: every node runs G=ceil(deg/16) groups; the
//          tail is the last group with per-edge predication (csr 16-pad makes
//          over-read safe) -- kills up to 3 serial csr->gather->compute
//          round-trips on the ~40% of nodes that are tail-heavy.
//      (b) group g+1's csr loads + 4 xl gathers issue BEFORE computing group
//          g (T14 split): compute covers next group's gather latency.
//      Kept from R14: fused scatter+gemm1 (slice<->XCD binding, clean csr
//      writes), global-Wc fused classifier (no LDS, conflicts=0), fma_mix
//      attn math, h1 fp16, setprio MFMA.
// ---------------------------------------------------------------------------

#define LOG2E 1.4426950408889634f
#define AST 40  // LDS row stride in shorts (80B rows; fragment reads 2-way=free)

typedef short bf16x8 __attribute__((ext_vector_type(8)));
typedef float f32x4 __attribute__((ext_vector_type(4)));

__device__ __forceinline__ unsigned short f2bf(float f) {
  union { float f; unsigned u; } x; x.f = f;
  unsigned r = x.u + 0x7fffu + ((x.u >> 16) & 1u);
  return (unsigned short)(r >> 16);
}
__device__ __forceinline__ float bf2f(unsigned short h) {
  union { unsigned u; float f; } x; x.u = ((unsigned)h) << 16;
  return x.f;
}
__device__ __forceinline__ void split4(float4 v, ushort4& h, ushort4& l) {
  h.x = f2bf(v.x); l.x = f2bf(v.x - bf2f(h.x));
  h.y = f2bf(v.y); l.y = f2bf(v.y - bf2f(h.y));
  h.z = f2bf(v.z); l.z = f2bf(v.z - bf2f(h.z));
  h.w = f2bf(v.w); l.w = f2bf(v.w - bf2f(h.w));
}

// ---- v_fma_mix_f32 helpers: d = a * (f16 half of b) + c, all-f32 accum ----
__device__ __forceinline__ float mixlo(float a, unsigned b, float c) {
  float d;
  asm("v_fma_mix_f32 %0, %1, %2, %3 op_sel_hi:[0,1,0]"
      : "=v"(d) : "v"(a), "v"(b), "v"(c));
  return d;
}
__device__ __forceinline__ float mixhi(float a, unsigned b, float c) {
  float d;
  asm("v_fma_mix_f32 %0, %1, %2, %3 op_sel:[0,1,0] op_sel_hi:[0,1,0]"
      : "=v"(d) : "v"(a), "v"(b), "v"(c));
  return d;
}
__device__ __forceinline__ float mixlo_abs(float a, unsigned b, float c) {
  float d;
  asm("v_fma_mix_f32 %0, %1, |%2|, %3 op_sel_hi:[0,1,0]"
      : "=v"(d) : "v"(a), "v"(b), "v"(c));
  return d;
}
__device__ __forceinline__ float mixhi_abs(float a, unsigned b, float c) {
  float d;
  asm("v_fma_mix_f32 %0, %1, |%2|, %3 op_sel:[0,1,0] op_sel_hi:[0,1,0]"
      : "=v"(d) : "v"(a), "v"(b), "v"(c));
  return d;
}
__device__ __forceinline__ unsigned pk_add(unsigned a, unsigned b) {
  union { unsigned u; __half2 h; } x, y, r;
  x.u = a; y.u = b;
  r.h = __hadd2(x.h, y.h);
  return r.u;
}

// e = sum_k a06[k]*t + a04[k]*|t| over 8 fp16 channels (t = xl+xr)
__device__ __forceinline__ float edot(uint4 raw, const unsigned* hxr,
                                      const float* a06, const float* a04) {
  const unsigned* xp = (const unsigned*)&raw;
  float ea = 0.f, eb = 0.f;
#pragma unroll
  for (int j = 0; j < 4; ++j) {
    unsigned tw = pk_add(xp[j], hxr[j]);
    ea = mixlo(a06[2 * j], tw, ea);
    ea = mixlo_abs(a04[2 * j], tw, ea);
    eb = mixhi(a06[2 * j + 1], tw, eb);
    eb = mixhi_abs(a04[2 * j + 1], tw, eb);
  }
  return ea + eb;
}
__device__ __forceinline__ void accupd(float p, uint4 raw, float* acc) {
  const unsigned* xp = (const unsigned*)&raw;
#pragma unroll
  for (int j = 0; j < 4; ++j) {
    acc[2 * j] = mixlo(p, xp[j], acc[2 * j]);
    acc[2 * j + 1] = mixhi(p, xp[j], acc[2 * j + 1]);
  }
}

// ------------------------------ CSR build ----------------------------------

__global__ __launch_bounds__(256) void zero_i32(int* __restrict__ p, int n) {
  int i = blockIdx.x * 256 + threadIdx.x;
  if (i < n) p[i] = 0;
}

// per-block scan of (cnt[i]+1)  (+1 = self loop slot)
__global__ __launch_bounds__(256) void scan_blk(const int* __restrict__ cnt,
                                                int* __restrict__ excl,
                                                int* __restrict__ bsum, int n) {
  __shared__ int s[256];
  int t = threadIdx.x, i = blockIdx.x * 256 + t;
  int v = (i < n) ? (cnt[i] + 1) : 0;
  s[t] = v;
  __syncthreads();
#pragma unroll
  for (int off = 1; off < 256; off <<= 1) {
    int u = (t >= off) ? s[t - off] : 0;
    __syncthreads();
    s[t] += u;
    __syncthreads();
  }
  if (i < n) excl[i] = s[t] - v;
  if (t == 255) bsum[blockIdx.x] = s[255];
}

__global__ __launch_bounds__(256) void scan_bsum(int* __restrict__ bsum, int nb,
                                                 int* __restrict__ row_start, int n) {
  __shared__ int s[256];
  int t = threadIdx.x;
  int v = (t < nb) ? bsum[t] : 0;
  s[t] = v;
  __syncthreads();
#pragma unroll
  for (int off = 1; off < 256; off <<= 1) {
    int u = (t >= off) ? s[t - off] : 0;
    __syncthreads();
    s[t] += u;
    __syncthreads();
  }
  if (t < nb) bsum[t] = s[t] - v;
  if (t == 255) row_start[n] = s[255];
}

// add block offsets; write self-loop entry; wpos starts past it; zero csr pad
__global__ __launch_bounds__(256) void scan_add(int* __restrict__ row_start,
                                                const int* __restrict__ bsum,
                                                int* __restrict__ wpos,
                                                int* __restrict__ csr,
                                                int n, int padBase) {
  int i = blockIdx.x * 256 + threadIdx.x;
  if (i < n) {
    int r = row_start[i] + bsum[blockIdx.x];
    row_start[i] = r;
    wpos[i] = r + 1;
    csr[r] = i;  // self loop first in each row
  }
  if (blockIdx.x == 0 && threadIdx.x < 16) csr[padBase + threadIdx.x] = 0;
}

// --------------------- weight convert + degree count -----------------------
// blocks 0..255: split-bf16 weight transpose (both layers)
// blocks 256.. : edge-degree count (independent work, merged launch)
__global__ __launch_bounds__(256) void convert_count(
    const float* __restrict__ Wl1, const float* __restrict__ Wr1,
    const float* __restrict__ Wl2, const float* __restrict__ Wr2,
    unsigned short* __restrict__ BT1h, unsigned short* __restrict__ BT1l,
    unsigned short* __restrict__ BT2h, unsigned short* __restrict__ BT2l,
    const int* __restrict__ dst, int* __restrict__ cnt, int E) {
  int b = blockIdx.x;
  if (b >= 256) {
    int i = (b - 256) * 256 + threadIdx.x;
    if (i < E) atomicAdd(&cnt[dst[i]], 1);
    return;
  }
  const float* Wl = (b < 128) ? Wl1 : Wl2;
  const float* Wr = (b < 128) ? Wr1 : Wr2;
  unsigned short* BTh = (b < 128) ? BT1h : BT2h;
  unsigned short* BTl = (b < 128) ? BT1l : BT2l;
  int idx = (b & 127) * 256 + threadIdx.x;  // 0..32767
  int col = idx >> 7, k = idx & 127;
  float v = (col < 128) ? Wl[k * 128 + col] : Wr[k * 128 + (col - 128)];
  unsigned short h = f2bf(v);
  BTh[idx] = h;
  BTl[idx] = f2bf(v - bf2f(h));
}

// ------------------------ MFMA GEMM (+fused scatter) -----------------------
// C[N x 256] = A[N x 128] @ W[128 x 256], split-bf16 3-term; C stored fp16.
// Block = 128 rows x 128 cols. 4 waves, each 64x64 (16 acc tiles).
// FUSE=1: grid also carries scatter blocks (5 of every 9). Scatter slice is
// the REAL blockIdx&7 (== XCD on round-robin dispatch) so each csr slice is
// written by exactly one XCD's L2; chunk = rank among same-slice blocks.
enum { IN_F32 = 0, IN_F16 = 1 };
#define NSCAT 1152
#define NCHUNK 128
template <int MODE, int FUSE>
__global__ __launch_bounds__(256) void gemm_mfma(
    const float* __restrict__ Af, const __half* __restrict__ Af16,
    const unsigned short* __restrict__ BTh, const unsigned short* __restrict__ BTl,
    __half* __restrict__ Cl, __half* __restrict__ Cr, int nrows,
    const int* __restrict__ esrc, const int* __restrict__ edst,
    int* __restrict__ wpos, int* __restrict__ csr, int E, int sliceSize) {
  __shared__ __align__(16) unsigned short smem[4 * 128 * AST];
  int tid = threadIdx.x;
  int bx, by;
  if (FUSE) {
    int g = blockIdx.x / 9, r = blockIdx.x - g * 9;
    if (r < 5) {  // ---- scatter role ----
      int sid = g * 5 + r;
      if (sid < NSCAT) {
        int slice = blockIdx.x & 7;  // == XCD (round-robin dispatch)
        // rank among scatter blocks with the same slice, ordered by g:
        // block (g',r') has slice (g'+r')&7; per g' at most one r'<5 matches.
        int chunk = (g >> 3) * 5;
        for (int gp = g & ~7; gp < g; ++gp)
          chunk += (((slice - gp) & 7) < 5) ? 1 : 0;
        if (chunk < NCHUNK) {
          int per = (E + NCHUNK - 1) / NCHUNK;
          int b0 = chunk * per;
          int ee = min(b0 + per, E);
          int lo = slice * sliceSize, hi = lo + sliceSize;
          int i = b0 + tid;
          // 4x-batched scan: 4 independent dst loads in flight
          for (; i + 768 < ee; i += 1024) {
            int d0 = edst[i];
            int d1 = edst[i + 256];
            int d2 = edst[i + 512];
            int d3 = edst[i + 768];
            if (d0 >= lo && d0 < hi) {
              int s = esrc[i];
              int p = atomicAdd(&wpos[d0], 1); csr[p] = s;
            }
            if (d1 >= lo && d1 < hi) {
              int s = esrc[i + 256];
              int p = atomicAdd(&wpos[d1], 1); csr[p] = s;
            }
            if (d2 >= lo && d2 < hi) {
              int s = esrc[i + 512];
              int p = atomicAdd(&wpos[d2], 1); csr[p] = s;
            }
            if (d3 >= lo && d3 < hi) {
              int s = esrc[i + 768];
              int p = atomicAdd(&wpos[d3], 1); csr[p] = s;
            }
          }
          for (; i < ee; i += 256) {
            int d = edst[i];
            if (d >= lo && d < hi) {
              int s = esrc[i];
              int p = atomicAdd(&wpos[d], 1); csr[p] = s;
            }
          }
        }
      }
      return;
    }
    int gid = g * 4 + (r - 5);  // ---- gemm role ----
    int nbx = (nrows + 127) >> 7;
    if (gid >= nbx * 2) return;
    bx = gid >> 1;
    by = gid & 1;
  } else {
    bx = blockIdx.x;
    by = blockIdx.y;
  }

  unsigned short* sAh = smem;
  unsigned short* sAl = smem + 5120;
  unsigned short* sBh = smem + 10240;
  unsigned short* sBl = smem + 15360;

  int wave = tid >> 6, lane = tid & 63;
  int rowBase = bx * 128;
  int colBase = by * 128;
  int rowHalf = (wave >> 1) * 64;
  int colHalf = (wave & 1) * 64;
  int l15 = lane & 15, quad = lane >> 4;

  f32x4 acc[4][4];
#pragma unroll
  for (int m = 0; m < 4; ++m)
#pragma unroll
    for (int n = 0; n < 4; ++n) acc[m][n] = (f32x4){0.f, 0.f, 0.f, 0.f};

  for (int kc = 0; kc < 4; ++kc) {
    // stage A: 128 rows x 32 k (hi+lo); idx 0..511, 8 k-elems each
#pragma unroll
    for (int i = 0; i < 2; ++i) {
      int idx = tid + i * 256;
      int row = idx >> 2, seg = idx & 3;
      int gr = rowBase + row;
      float4 v0 = make_float4(0.f, 0.f, 0.f, 0.f), v1 = v0;
      if (MODE == IN_F32) {
        if (gr < nrows) {
          v0 = *(const float4*)&Af[(size_t)gr * 128 + kc * 32 + seg * 8];
          v1 = *(const float4*)&Af[(size_t)gr * 128 + kc * 32 + seg * 8 + 4];
        }
      } else {
        if (gr < nrows) {
          uint4 raw = *(const uint4*)&Af16[(size_t)gr * 128 + kc * 32 + seg * 8];
          const __half* hp = (const __half*)&raw;
          v0 = make_float4(__half2float(hp[0]), __half2float(hp[1]),
                           __half2float(hp[2]), __half2float(hp[3]));
          v1 = make_float4(__half2float(hp[4]), __half2float(hp[5]),
                           __half2float(hp[6]), __half2float(hp[7]));
        }
      }
      ushort4 h0, l0, h1, l1;
      split4(v0, h0, l0);
      split4(v1, h1, l1);
      *(ushort4*)&sAh[row * AST + seg * 8] = h0;
      *(ushort4*)&sAh[row * AST + seg * 8 + 4] = h1;
      *(ushort4*)&sAl[row * AST + seg * 8] = l0;
      *(ushort4*)&sAl[row * AST + seg * 8 + 4] = l1;
    }
    // stage B: 128 cols x 32 k (hi+lo); idx 0..511
#pragma unroll
    for (int i = 0; i < 2; ++i) {
      int idx = tid + i * 256;
      int col = idx >> 2, seg = idx & 3;
      *(uint4*)&sBh[col * AST + seg * 8] =
          *(const uint4*)&BTh[(size_t)(colBase + col) * 128 + kc * 32 + seg * 8];
      *(uint4*)&sBl[col * AST + seg * 8] =
          *(const uint4*)&BTl[(size_t)(colBase + col) * 128 + kc * 32 + seg * 8];
    }
    __syncthreads();

    bf16x8 afh[4], afl[4], bfh[4], bfl[4];
#pragma unroll
    for (int m = 0; m < 4; ++m) {
      int r = rowHalf + m * 16 + l15;
      afh[m] = *(const bf16x8*)&sAh[r * AST + quad * 8];
      afl[m] = *(const bf16x8*)&sAl[r * AST + quad * 8];
    }
#pragma unroll
    for (int n = 0; n < 4; ++n) {
      int cc = colHalf + n * 16 + l15;
      bfh[n] = *(const bf16x8*)&sBh[cc * AST + quad * 8];
      bfl[n] = *(const bf16x8*)&sBl[cc * AST + quad * 8];
    }
    __builtin_amdgcn_s_setprio(1);
#pragma unroll
    for (int m = 0; m < 4; ++m)
#pragma unroll
      for (int n = 0; n < 4; ++n) {
        acc[m][n] = __builtin_amdgcn_mfma_f32_16x16x32_bf16(afh[m], bfh[n], acc[m][n], 0, 0, 0);
        acc[m][n] = __builtin_amdgcn_mfma_f32_16x16x32_bf16(afh[m], bfl[n], acc[m][n], 0, 0, 0);
        acc[m][n] = __builtin_amdgcn_mfma_f32_16x16x32_bf16(afl[m], bfh[n], acc[m][n], 0, 0, 0);
      }
    __builtin_amdgcn_s_setprio(0);
    __syncthreads();
  }

  __half* __restrict__ C = (by == 0) ? Cl : Cr;
#pragma unroll
  for (int m = 0; m < 4; ++m)
#pragma unroll
    for (int r = 0; r < 4; ++r) {
      int grow = rowBase + rowHalf + m * 16 + quad * 4 + r;
      if (grow < nrows) {
#pragma unroll
        for (int n = 0; n < 4; ++n)
          C[(size_t)grow * 128 + colHalf + n * 16 + l15] = __float2half(acc[m][n][r]);
      }
    }
}

// ------------------------------ attention ----------------------------------
// One wave per node; 16 lanes/edge (8 ch/lane, one b128 fp16 load);
// 4 edge-slots/wave. 2-stage pipelined group loop: group g+1's csr + gathers
// issue before computing group g; tail = last group with per-edge
// predication (csr 16-pad makes over-read safe). Inner math: v_pk_add_f16 +
// v_fma_mix_f32. Optional fused classifier via global Wc (L1-resident).
__global__ __launch_bounds__(256) void gat_attn(const __half* __restrict__ xl,
                                                const __half* __restrict__ xr,
                                                const int* __restrict__ row_start,
                                                const int* __restrict__ csr,
                                                const float* __restrict__ att,
                                                const float* __restrict__ bias,
                                                float* __restrict__ ofp,
                                                __half* __restrict__ oh16,
                                                const float* __restrict__ Wc,
                                                const float* __restrict__ bc,
                                                float* __restrict__ logits,
                                                int n_nodes) {
  int tid = threadIdx.x;
  int node = blockIdx.x * 4 + (tid >> 6);
  if (node >= n_nodes) return;
  int lane = tid & 63;
  int slot = lane >> 4;
  int l15 = lane & 15;
  int c0 = l15 * 8;

  // xr row kept packed fp16 (4 half2 words)
  unsigned hxr[4];
  {
    uint4 raw = *(const uint4*)&xr[(size_t)node * 128 + c0];
    const unsigned* q = (const unsigned*)&raw;
    hxr[0] = q[0]; hxr[1] = q[1]; hxr[2] = q[2]; hxr[3] = q[3];
  }
  // att row, pre-scaled: a06 = 0.6*log2e*a, a04 = 0.4*log2e*a
  float a06[8], a04[8];
  {
    float4 a0 = *(const float4*)&att[c0];
    float4 a1 = *(const float4*)&att[c0 + 4];
    float av[8] = {a0.x, a0.y, a0.z, a0.w, a1.x, a1.y, a1.z, a1.w};
    const float C06 = 0.6f * LOG2E, C04 = 0.4f * LOG2E;
#pragma unroll
    for (int k = 0; k < 8; ++k) { a06[k] = av[k] * C06; a04[k] = av[k] * C04; }
  }

  float acc[8];
#pragma unroll
  for (int k = 0; k < 8; ++k) acc[k] = 0.f;
  float lsum = 0.f;

  int beg = row_start[node], end = row_start[node + 1];
  int deg = end - beg;          // includes self; >= 1
  int G = (deg + 15) >> 4;      // 16-edge groups (last one predicated)
  int sb = beg + 4 * slot;

#define XLROW(S) (*(const uint4*)&xl[(size_t)(unsigned)(S)*128 + c0])

  // prologue: group 0 csr + gathers (csr padded by 16 -> over-read safe)
  int k0 = csr[sb], k1 = csr[sb + 1], k2 = csr[sb + 2], k3 = csr[sb + 3];
  uint4 r0 = XLROW(k0), r1 = XLROW(k1), r2 = XLROW(k2), r3 = XLROW(k3);

  int g = 0;
  while (true) {
    bool more = (g + 1 < G);
    uint4 n0, n1, n2, n3;
    if (more) {  // issue next group's csr + gathers before computing this one
      int nb = sb + ((g + 1) << 4);
      int d0 = csr[nb], d1 = csr[nb + 1], d2 = csr[nb + 2], d3 = csr[nb + 3];
      n0 = XLROW(d0); n1 = XLROW(d1); n2 = XLROW(d2); n3 = XLROW(d3);
    }
    float e0 = edot(r0, hxr, a06, a04);
    float e1 = edot(r1, hxr, a06, a04);
    float e2 = edot(r2, hxr, a06, a04);
    float e3 = edot(r3, hxr, a06, a04);
    e0 += __shfl_xor(e0, 1); e1 += __shfl_xor(e1, 1);
    e2 += __shfl_xor(e2, 1); e3 += __shfl_xor(e3, 1);
    e0 += __shfl_xor(e0, 2); e1 += __shfl_xor(e1, 2);
    e2 += __shfl_xor(e2, 2); e3 += __shfl_xor(e3, 2);
    int ib = sb + (g << 4);  // this group's first edge index for this slot
    float p0 = (ib < end) ? __builtin_amdgcn_exp2f(e0) : 0.f;
    float p1 = (ib + 1 < end) ? __builtin_amdgcn_exp2f(e1) : 0.f;
    float p2 = (ib + 2 < end) ? __builtin_amdgcn_exp2f(e2) : 0.f;
    float p3 = (ib + 3 < end) ? __builtin_amdgcn_exp2f(e3) : 0.f;
    lsum += (p0 + p1) + (p2 + p3);
    accupd(p0, r0, acc);
    accupd(p1, r1, acc);
    accupd(p2, r2, acc);
    accupd(p3, r3, acc);
    if (!more) break;
    r0 = n0; r1 = n1; r2 = n2; r3 = n3;
    ++g;
  }
#undef XLROW

  // fused-classifier weight loads: issue early so L1/L2 latency overlaps the
  // slot-merge shuffle chain. Wc is 8KB -> L1-resident, conflict-free.
  int ob = slot * 4;
  float4 wv[8];
  if (logits) {
#pragma unroll
    for (int k = 0; k < 8; ++k)
      wv[k] = *(const float4*)&Wc[(size_t)(c0 + k) * 16 + ob];
  }

  // merge the 4 slots (same channels live in lanes with equal l15)
  lsum += __shfl_xor(lsum, 16);
  lsum += __shfl_xor(lsum, 32);
#pragma unroll
  for (int k = 0; k < 8; ++k) {
    acc[k] += __shfl_xor(acc[k], 16);
    acc[k] += __shfl_xor(acc[k], 32);
  }

  // all lanes compute o (slots redundant; needed lane-local for classifier)
  float o[8];
  {
    float4 b0v = *(const float4*)&bias[c0];
    float4 b1v = *(const float4*)&bias[c0 + 4];
    float bv[8] = {b0v.x, b0v.y, b0v.z, b0v.w, b1v.x, b1v.y, b1v.z, b1v.w};
    float inv = 1.f / (lsum + 1e-16f);
#pragma unroll
    for (int k = 0; k < 8; ++k) {
      float v = fmaf(acc[k], inv, bv[k]);
      o[k] = fmaf(0.495f, fabsf(v), 0.505f * v);  // leaky 0.01
    }
  }

  if (slot == 0) {
    if (ofp) {
      *(float4*)&ofp[(size_t)node * 128 + c0] = make_float4(o[0], o[1], o[2], o[3]);
      *(float4*)&ofp[(size_t)node * 128 + c0 + 4] = make_float4(o[4], o[5], o[6], o[7]);
    }
    if (oh16) {
      ushort4 ha, hb;
      ha.x = __half_as_ushort(__float2half(o[0]));
      ha.y = __half_as_ushort(__float2half(o[1]));
      ha.z = __half_as_ushort(__float2half(o[2]));
      ha.w = __half_as_ushort(__float2half(o[3]));
      hb.x = __half_as_ushort(__float2half(o[4]));
      hb.y = __half_as_ushort(__float2half(o[5]));
      hb.z = __half_as_ushort(__float2half(o[6]));
      hb.w = __half_as_ushort(__float2half(o[7]));
      *(ushort4*)&oh16[(size_t)node * 128 + c0] = ha;
      *(ushort4*)&oh16[(size_t)node * 128 + c0 + 4] = hb;
    }
  }

  if (logits) {  // fused classifier: outputs ob..ob+3 partial over 8 chans
    float pj0 = 0.f, pj1 = 0.f, pj2 = 0.f, pj3 = 0.f;
#pragma unroll
    for (int k = 0; k < 8; ++k) {
      pj0 = fmaf(o[k], wv[k].x, pj0);
      pj1 = fmaf(o[k], wv[k].y, pj1);
      pj2 = fmaf(o[k], wv[k].z, pj2);
      pj3 = fmaf(o[k], wv[k].w, pj3);
    }
#pragma unroll
    for (int m = 1; m < 16; m <<= 1) {
      pj0 += __shfl_xor(pj0, m);
      pj1 += __shfl_xor(pj1, m);
      pj2 += __shfl_xor(pj2, m);
      pj3 += __shfl_xor(pj3, m);
    }
    if (l15 < 4) {
      float pv = (l15 == 0) ? pj0 : (l15 == 1) ? pj1 : (l15 == 2) ? pj2 : pj3;
      logits[(size_t)node * 16 + ob + l15] = pv + bc[ob + l15];
    }
  }
}

// ---------------------------------------------------------------------------

extern "C" void kernel_launch(void* const* d_in, const int* in_sizes, int n_in,
                              void* d_out, int out_size, void* d_ws, size_t ws_size,
                              hipStream_t stream) {
  const float* x    = (const float*)d_in[0];
  const int*   ei   = (const int*)d_in[1];
  const float* Wl1  = (const float*)d_in[3];
  const float* Wr1  = (const float*)d_in[4];
  const float* att1 = (const float*)d_in[5];
  const float* b1   = (const float*)d_in[6];
  const float* Wl2  = (const float*)d_in[7];
  const float* Wr2  = (const float*)d_in[8];
  const float* att2 = (const float*)d_in[9];
  const float* b2   = (const float*)d_in[10];
  const float* Wc   = (const float*)d_in[11];
  const float* bc   = (const float*)d_in[12];

  const int N = in_sizes[0] / 128;
  const int E = in_sizes[1] / 2;

  float* outp   = (float*)d_out;
  float* logits = outp;                   // N*16 fp32
  float* hout   = outp + (size_t)N * 16;  // N*128 fp32 region
  // h1 (fp16) staged in the hout region (overwritten by fp32 h2 later)
  __half* h1f16 = (__half*)hout;

  char* ws = (char*)d_ws;
  __half* xlbuf = (__half*)ws;                ws += (size_t)N * 128 * 2;
  __half* xrbuf = (__half*)ws;                ws += (size_t)N * 128 * 2;
  unsigned short* WT1h = (unsigned short*)ws; ws += 256 * 128 * 2;
  unsigned short* WT1l = (unsigned short*)ws; ws += 256 * 128 * 2;
  unsigned short* WT2h = (unsigned short*)ws; ws += 256 * 128 * 2;
  unsigned short* WT2l = (unsigned short*)ws; ws += 256 * 128 * 2;
  int* cnt       = (int*)ws;                  ws += (size_t)N * 4;
  int* row_start = (int*)ws;                  ws += (size_t)(N + 1) * 4;
  int* wpos      = (int*)ws;                  ws += (size_t)N * 4;
  int* bsum      = (int*)ws;                  ws += 256 * 4;
  int* csr       = (int*)ws;                  ws += (size_t)(E + N + 16) * 4;

  const int* esrc = ei;
  const int* edst = ei + E;

  int gN = (N + 255) / 256, gE = (E + 255) / 256;
  int gAttn = (N + 3) / 4;
  int sliceSize = (N + 7) / 8;

  int nbx = (N + 127) / 128;
  int nGemm = nbx * 2;
  int groups = (NSCAT + 4) / 5;  // 231 -> covers >=128 chunks per slice
  int g2 = (nGemm + 3) / 4;
  if (g2 > groups) groups = g2;
  int gFused = groups * 9;

  // CSR build (self loops embedded: counts+1, csr[beg]=node)
  zero_i32<<<gN, 256, 0, stream>>>(cnt, N);
  convert_count<<<256 + gE, 256, 0, stream>>>(Wl1, Wr1, Wl2, Wr2,
                                              WT1h, WT1l, WT2h, WT2l,
                                              edst, cnt, E);
  scan_blk<<<gN, 256, 0, stream>>>(cnt, row_start, bsum, N);
  scan_bsum<<<1, 256, 0, stream>>>(bsum, gN, row_start, N);
  scan_add<<<gN, 256, 0, stream>>>(row_start, bsum, wpos, csr, N, E + N);

  // layer 1 GEMM (fp32 x, split inline) fused with CSR scatter
  gemm_mfma<IN_F32, 1><<<gFused, 256, 0, stream>>>(
      x, nullptr, WT1h, WT1l, xlbuf, xrbuf, N,
      esrc, edst, wpos, csr, E, sliceSize);
  gat_attn<<<gAttn, 256, 0, stream>>>(xlbuf, xrbuf, row_start, csr, att1, b1,
                                      nullptr, h1f16, nullptr, nullptr, nullptr, N);

  // layer 2 (reads fp16 h1, splits inline; writes fp16 xl/xr)
  gemm_mfma<IN_F16, 0><<<dim3(nbx, 2), 256, 0, stream>>>(
      nullptr, h1f16, WT2h, WT2l, xlbuf, xrbuf, N,
      nullptr, nullptr, nullptr, nullptr, 0, 0);
  // layer-2 attention with fused classifier
  gat_attn<<<gAttn, 256, 0, stream>>>(xlbuf, xrbuf, row_start, csr, att2, b2,
                                      hout, nullptr, Wc, bc, logits, N);
}

// Round 6
// 314.294 us; speedup vs baseline: 1.0686x; 1.0484x over previous
//
#include <hip/hip_runtime.h>
#include <hip/hip_fp16.h>

// ---------------------------------------------------------------------------
// GATv2 x2 + classifier. N=50000, E=800000, IN=128, HEADS=4, HID=32, OUT=16.
// R16: attn + classifier REVERTED to the R10-proven forms. The R12 attn
//      rewrite (fma_mix inline asm + 4-edge batch) was never isolated and
//      the round arc shows it was the regression: attn2 46.3->68.7->84us
//      while absolute VALU-busy time ROSE at constant FETCH; every
//      classifier-fusion variant cost 18-35us (LDS 16-way conflicts or
//      global-Wc L1 scatter serialization). Reverted to: scalar
//      __half2float+fmaf edge bodies, serial 16-edge main + 4-edge tail,
//      slot0-only epilogue, separate classifier kernel (~13us, proven).
//      KEPT (verified): fused scatter+gemm1 dispatch with slice<->XCD static
//      binding (csr writes clean, ~62-66us vs 87 serialized), 4x-batched
//      scatter scan, convert+count merged launch, h1 fp16 staging, setprio
//      around gemm MFMA cluster.
// ---------------------------------------------------------------------------

#define LOG2E 1.4426950408889634f
#define AST 40  // LDS row stride in shorts (80B rows; fragment reads 2-way=free)

typedef short bf16x8 __attribute__((ext_vector_type(8)));
typedef float f32x4 __attribute__((ext_vector_type(4)));

__device__ __forceinline__ unsigned short f2bf(float f) {
  union { float f; unsigned u; } x; x.f = f;
  unsigned r = x.u + 0x7fffu + ((x.u >> 16) & 1u);
  return (unsigned short)(r >> 16);
}
__device__ __forceinline__ float bf2f(unsigned short h) {
  union { unsigned u; float f; } x; x.u = ((unsigned)h) << 16;
  return x.f;
}
__device__ __forceinline__ void split4(float4 v, ushort4& h, ushort4& l) {
  h.x = f2bf(v.x); l.x = f2bf(v.x - bf2f(h.x));
  h.y = f2bf(v.y); l.y = f2bf(v.y - bf2f(h.y));
  h.z = f2bf(v.z); l.z = f2bf(v.z - bf2f(h.z));
  h.w = f2bf(v.w); l.w = f2bf(v.w - bf2f(h.w));
}

// ------------------------------ CSR build ----------------------------------

__global__ __launch_bounds__(256) void zero_i32(int* __restrict__ p, int n) {
  int i = blockIdx.x * 256 + threadIdx.x;
  if (i < n) p[i] = 0;
}

// per-block scan of (cnt[i]+1)  (+1 = self loop slot)
__global__ __launch_bounds__(256) void scan_blk(const int* __restrict__ cnt,
                                                int* __restrict__ excl,
                                                int* __restrict__ bsum, int n) {
  __shared__ int s[256];
  int t = threadIdx.x, i = blockIdx.x * 256 + t;
  int v = (i < n) ? (cnt[i] + 1) : 0;
  s[t] = v;
  __syncthreads();
#pragma unroll
  for (int off = 1; off < 256; off <<= 1) {
    int u = (t >= off) ? s[t - off] : 0;
    __syncthreads();
    s[t] += u;
    __syncthreads();
  }
  if (i < n) excl[i] = s[t] - v;
  if (t == 255) bsum[blockIdx.x] = s[255];
}

__global__ __launch_bounds__(256) void scan_bsum(int* __restrict__ bsum, int nb,
                                                 int* __restrict__ row_start, int n) {
  __shared__ int s[256];
  int t = threadIdx.x;
  int v = (t < nb) ? bsum[t] : 0;
  s[t] = v;
  __syncthreads();
#pragma unroll
  for (int off = 1; off < 256; off <<= 1) {
    int u = (t >= off) ? s[t - off] : 0;
    __syncthreads();
    s[t] += u;
    __syncthreads();
  }
  if (t < nb) bsum[t] = s[t] - v;
  if (t == 255) row_start[n] = s[255];
}

// add block offsets; write self-loop entry; wpos starts past it; zero csr pad
__global__ __launch_bounds__(256) void scan_add(int* __restrict__ row_start,
                                                const int* __restrict__ bsum,
                                                int* __restrict__ wpos,
                                                int* __restrict__ csr,
                                                int n, int padBase) {
  int i = blockIdx.x * 256 + threadIdx.x;
  if (i < n) {
    int r = row_start[i] + bsum[blockIdx.x];
    row_start[i] = r;
    wpos[i] = r + 1;
    csr[r] = i;  // self loop first in each row
  }
  if (blockIdx.x == 0 && threadIdx.x < 16) csr[padBase + threadIdx.x] = 0;
}

// --------------------- weight convert + degree count -----------------------
// blocks 0..255: split-bf16 weight transpose (both layers)
// blocks 256.. : edge-degree count (independent work, merged launch)
__global__ __launch_bounds__(256) void convert_count(
    const float* __restrict__ Wl1, const float* __restrict__ Wr1,
    const float* __restrict__ Wl2, const float* __restrict__ Wr2,
    unsigned short* __restrict__ BT1h, unsigned short* __restrict__ BT1l,
    unsigned short* __restrict__ BT2h, unsigned short* __restrict__ BT2l,
    const int* __restrict__ dst, int* __restrict__ cnt, int E) {
  int b = blockIdx.x;
  if (b >= 256) {
    int i = (b - 256) * 256 + threadIdx.x;
    if (i < E) atomicAdd(&cnt[dst[i]], 1);
    return;
  }
  const float* Wl = (b < 128) ? Wl1 : Wl2;
  const float* Wr = (b < 128) ? Wr1 : Wr2;
  unsigned short* BTh = (b < 128) ? BT1h : BT2h;
  unsigned short* BTl = (b < 128) ? BT1l : BT2l;
  int idx = (b & 127) * 256 + threadIdx.x;  // 0..32767
  int col = idx >> 7, k = idx & 127;
  float v = (col < 128) ? Wl[k * 128 + col] : Wr[k * 128 + (col - 128)];
  unsigned short h = f2bf(v);
  BTh[idx] = h;
  BTl[idx] = f2bf(v - bf2f(h));
}

// ------------------------ MFMA GEMM (+fused scatter) -----------------------
// C[N x 256] = A[N x 128] @ W[128 x 256], split-bf16 3-term; C stored fp16.
// Block = 128 rows x 128 cols. 4 waves, each 64x64 (16 acc tiles).
// FUSE=1: grid also carries scatter blocks (5 of every 9). Scatter slice is
// the REAL blockIdx&7 (== XCD on round-robin dispatch) so each csr slice is
// written by exactly one XCD's L2; chunk = rank among same-slice blocks.
enum { IN_F32 = 0, IN_F16 = 1 };
#define NSCAT 1152
#define NCHUNK 128
template <int MODE, int FUSE>
__global__ __launch_bounds__(256) void gemm_mfma(
    const float* __restrict__ Af, const __half* __restrict__ Af16,
    const unsigned short* __restrict__ BTh, const unsigned short* __restrict__ BTl,
    __half* __restrict__ Cl, __half* __restrict__ Cr, int nrows,
    const int* __restrict__ esrc, const int* __restrict__ edst,
    int* __restrict__ wpos, int* __restrict__ csr, int E, int sliceSize) {
  __shared__ __align__(16) unsigned short smem[4 * 128 * AST];
  int tid = threadIdx.x;
  int bx, by;
  if (FUSE) {
    int g = blockIdx.x / 9, r = blockIdx.x - g * 9;
    if (r < 5) {  // ---- scatter role ----
      int sid = g * 5 + r;
      if (sid < NSCAT) {
        int slice = blockIdx.x & 7;  // == XCD (round-robin dispatch)
        // rank among scatter blocks with the same slice, ordered by g:
        // block (g',r') has slice (g'+r')&7; per g' at most one r'<5 matches.
        int chunk = (g >> 3) * 5;
        for (int gp = g & ~7; gp < g; ++gp)
          chunk += (((slice - gp) & 7) < 5) ? 1 : 0;
        if (chunk < NCHUNK) {
          int per = (E + NCHUNK - 1) / NCHUNK;
          int b0 = chunk * per;
          int ee = min(b0 + per, E);
          int lo = slice * sliceSize, hi = lo + sliceSize;
          int i = b0 + tid;
          // 4x-batched scan: 4 independent dst loads in flight
          for (; i + 768 < ee; i += 1024) {
            int d0 = edst[i];
            int d1 = edst[i + 256];
            int d2 = edst[i + 512];
            int d3 = edst[i + 768];
            if (d0 >= lo && d0 < hi) {
              int s = esrc[i];
              int p = atomicAdd(&wpos[d0], 1); csr[p] = s;
            }
            if (d1 >= lo && d1 < hi) {
              int s = esrc[i + 256];
              int p = atomicAdd(&wpos[d1], 1); csr[p] = s;
            }
            if (d2 >= lo && d2 < hi) {
              int s = esrc[i + 512];
              int p = atomicAdd(&wpos[d2], 1); csr[p] = s;
            }
            if (d3 >= lo && d3 < hi) {
              int s = esrc[i + 768];
              int p = atomicAdd(&wpos[d3], 1); csr[p] = s;
            }
          }
          for (; i < ee; i += 256) {
            int d = edst[i];
            if (d >= lo && d < hi) {
              int s = esrc[i];
              int p = atomicAdd(&wpos[d], 1); csr[p] = s;
            }
          }
        }
      }
      return;
    }
    int gid = g * 4 + (r - 5);  // ---- gemm role ----
    int nbx = (nrows + 127) >> 7;
    if (gid >= nbx * 2) return;
    bx = gid >> 1;
    by = gid & 1;
  } else {
    bx = blockIdx.x;
    by = blockIdx.y;
  }

  unsigned short* sAh = smem;
  unsigned short* sAl = smem + 5120;
  unsigned short* sBh = smem + 10240;
  unsigned short* sBl = smem + 15360;

  int wave = tid >> 6, lane = tid & 63;
  int rowBase = bx * 128;
  int colBase = by * 128;
  int rowHalf = (wave >> 1) * 64;
  int colHalf = (wave & 1) * 64;
  int l15 = lane & 15, quad = lane >> 4;

  f32x4 acc[4][4];
#pragma unroll
  for (int m = 0; m < 4; ++m)
#pragma unroll
    for (int n = 0; n < 4; ++n) acc[m][n] = (f32x4){0.f, 0.f, 0.f, 0.f};

  for (int kc = 0; kc < 4; ++kc) {
    // stage A: 128 rows x 32 k (hi+lo); idx 0..511, 8 k-elems each
#pragma unroll
    for (int i = 0; i < 2; ++i) {
      int idx = tid + i * 256;
      int row = idx >> 2, seg = idx & 3;
      int gr = rowBase + row;
      float4 v0 = make_float4(0.f, 0.f, 0.f, 0.f), v1 = v0;
      if (MODE == IN_F32) {
        if (gr < nrows) {
          v0 = *(const float4*)&Af[(size_t)gr * 128 + kc * 32 + seg * 8];
          v1 = *(const float4*)&Af[(size_t)gr * 128 + kc * 32 + seg * 8 + 4];
        }
      } else {
        if (gr < nrows) {
          uint4 raw = *(const uint4*)&Af16[(size_t)gr * 128 + kc * 32 + seg * 8];
          const __half* hp = (const __half*)&raw;
          v0 = make_float4(__half2float(hp[0]), __half2float(hp[1]),
                           __half2float(hp[2]), __half2float(hp[3]));
          v1 = make_float4(__half2float(hp[4]), __half2float(hp[5]),
                           __half2float(hp[6]), __half2float(hp[7]));
        }
      }
      ushort4 h0, l0, h1, l1;
      split4(v0, h0, l0);
      split4(v1, h1, l1);
      *(ushort4*)&sAh[row * AST + seg * 8] = h0;
      *(ushort4*)&sAh[row * AST + seg * 8 + 4] = h1;
      *(ushort4*)&sAl[row * AST + seg * 8] = l0;
      *(ushort4*)&sAl[row * AST + seg * 8 + 4] = l1;
    }
    // stage B: 128 cols x 32 k (hi+lo); idx 0..511
#pragma unroll
    for (int i = 0; i < 2; ++i) {
      int idx = tid + i * 256;
      int col = idx >> 2, seg = idx & 3;
      *(uint4*)&sBh[col * AST + seg * 8] =
          *(const uint4*)&BTh[(size_t)(colBase + col) * 128 + kc * 32 + seg * 8];
      *(uint4*)&sBl[col * AST + seg * 8] =
          *(const uint4*)&BTl[(size_t)(colBase + col) * 128 + kc * 32 + seg * 8];
    }
    __syncthreads();

    bf16x8 afh[4], afl[4], bfh[4], bfl[4];
#pragma unroll
    for (int m = 0; m < 4; ++m) {
      int r = rowHalf + m * 16 + l15;
      afh[m] = *(const bf16x8*)&sAh[r * AST + quad * 8];
      afl[m] = *(const bf16x8*)&sAl[r * AST + quad * 8];
    }
#pragma unroll
    for (int n = 0; n < 4; ++n) {
      int cc = colHalf + n * 16 + l15;
      bfh[n] = *(const bf16x8*)&sBh[cc * AST + quad * 8];
      bfl[n] = *(const bf16x8*)&sBl[cc * AST + quad * 8];
    }
    __builtin_amdgcn_s_setprio(1);
#pragma unroll
    for (int m = 0; m < 4; ++m)
#pragma unroll
      for (int n = 0; n < 4; ++n) {
        acc[m][n] = __builtin_amdgcn_mfma_f32_16x16x32_bf16(afh[m], bfh[n], acc[m][n], 0, 0, 0);
        acc[m][n] = __builtin_amdgcn_mfma_f32_16x16x32_bf16(afh[m], bfl[n], acc[m][n], 0, 0, 0);
        acc[m][n] = __builtin_amdgcn_mfma_f32_16x16x32_bf16(afl[m], bfh[n], acc[m][n], 0, 0, 0);
      }
    __builtin_amdgcn_s_setprio(0);
    __syncthreads();
  }

  __half* __restrict__ C = (by == 0) ? Cl : Cr;
#pragma unroll
  for (int m = 0; m < 4; ++m)
#pragma unroll
    for (int r = 0; r < 4; ++r) {
      int grow = rowBase + rowHalf + m * 16 + quad * 4 + r;
      if (grow < nrows) {
#pragma unroll
        for (int n = 0; n < 4; ++n)
          C[(size_t)grow * 128 + colHalf + n * 16 + l15] = __float2half(acc[m][n][r]);
      }
    }
}

// ------------------------------ attention ----------------------------------
// R10-proven form. One wave per node; 16 lanes/edge (8 ch/lane, one b128
// fp16 load); 4 edge-slots/wave. Main loop 16 edges/iter, tail 4 edges/iter.
// Self loop lives in csr (csr[beg] = node). Outputs fp32 and/or fp16.
__global__ __launch_bounds__(256) void gat_attn(const __half* __restrict__ xl,
                                                const __half* __restrict__ xr,
                                                const int* __restrict__ row_start,
                                                const int* __restrict__ csr,
                                                const float* __restrict__ att,
                                                const float* __restrict__ bias,
                                                float* __restrict__ ofp,
                                                __half* __restrict__ oh16,
                                                int n_nodes) {
  int node = blockIdx.x * 4 + (threadIdx.x >> 6);
  if (node >= n_nodes) return;
  int lane = threadIdx.x & 63;
  int slot = lane >> 4;
  int l15 = lane & 15;
  int c0 = l15 * 8;

  // xr row (fp16 -> fp32)
  float fxr[8];
  {
    uint4 raw = *(const uint4*)&xr[(size_t)node * 128 + c0];
    const __half* hp = (const __half*)&raw;
#pragma unroll
    for (int k = 0; k < 8; ++k) fxr[k] = __half2float(hp[k]);
  }
  // att row, pre-scaled: a06 = 0.6*log2e*a, a04 = 0.4*log2e*a
  float a06[8], a04[8];
  {
    float4 a0 = *(const float4*)&att[c0];
    float4 a1 = *(const float4*)&att[c0 + 4];
    float av[8] = {a0.x, a0.y, a0.z, a0.w, a1.x, a1.y, a1.z, a1.w};
    const float C06 = 0.6f * LOG2E, C04 = 0.4f * LOG2E;
#pragma unroll
    for (int k = 0; k < 8; ++k) { a06[k] = av[k] * C06; a04[k] = av[k] * C04; }
  }

  float acc[8];
#pragma unroll
  for (int k = 0; k < 8; ++k) acc[k] = 0.f;
  float lsum = 0.f;

#define EDGE_BODY(SRC, PVALID)                                                 \
  {                                                                            \
    uint4 raw = *(const uint4*)&xl[(size_t)(unsigned)(SRC)*128 + c0];          \
    const __half* hp = (const __half*)&raw;                                    \
    float e = 0.f;                                                             \
    _Pragma("unroll") for (int k = 0; k < 8; ++k) {                            \
      float t = __half2float(hp[k]) + fxr[k];                                  \
      e = fmaf(a06[k], t, e);                                                  \
      e = fmaf(a04[k], fabsf(t), e);                                           \
    }                                                                          \
    e += __shfl_xor(e, 1);                                                     \
    e += __shfl_xor(e, 2);                                                     \
    float p = (PVALID) ? __builtin_amdgcn_exp2f(e) : 0.f;                      \
    lsum += p;                                                                 \
    _Pragma("unroll") for (int k = 0; k < 8; ++k)                              \
        acc[k] = fmaf(p, __half2float(hp[k]), acc[k]);                         \
  }

  int beg = row_start[node], end = row_start[node + 1];
  int deg = end - beg;  // includes self
  int fullEnd = beg + (deg & ~15);

  for (int base = beg; base < fullEnd; base += 16) {
    int b0 = base + 4 * slot;
    int s0 = csr[b0], s1 = csr[b0 + 1], s2 = csr[b0 + 2], s3 = csr[b0 + 3];
    EDGE_BODY(s0, true);
    EDGE_BODY(s1, true);
    EDGE_BODY(s2, true);
    EDGE_BODY(s3, true);
  }
  for (int base = fullEnd; base < end; base += 4) {  // csr padded by 16
    int idx = base + slot;
    int src = csr[idx];
    EDGE_BODY(src, idx < end);
  }
#undef EDGE_BODY

  // merge the 4 slots (same channels live in lanes with equal l15)
  lsum += __shfl_xor(lsum, 16);
  lsum += __shfl_xor(lsum, 32);
#pragma unroll
  for (int k = 0; k < 8; ++k) {
    acc[k] += __shfl_xor(acc[k], 16);
    acc[k] += __shfl_xor(acc[k], 32);
  }

  if (slot == 0) {
    float4 b0v = *(const float4*)&bias[c0];
    float4 b1v = *(const float4*)&bias[c0 + 4];
    float bv[8] = {b0v.x, b0v.y, b0v.z, b0v.w, b1v.x, b1v.y, b1v.z, b1v.w};
    float inv = 1.f / (lsum + 1e-16f);
    float o[8];
#pragma unroll
    for (int k = 0; k < 8; ++k) {
      float v = fmaf(acc[k], inv, bv[k]);
      o[k] = fmaf(0.495f, fabsf(v), 0.505f * v);  // leaky 0.01
    }
    if (ofp) {
      *(float4*)&ofp[(size_t)node * 128 + c0] = make_float4(o[0], o[1], o[2], o[3]);
      *(float4*)&ofp[(size_t)node * 128 + c0 + 4] = make_float4(o[4], o[5], o[6], o[7]);
    }
    if (oh16) {
      ushort4 ha, hb;
      ha.x = __half_as_ushort(__float2half(o[0]));
      ha.y = __half_as_ushort(__float2half(o[1]));
      ha.z = __half_as_ushort(__float2half(o[2]));
      ha.w = __half_as_ushort(__float2half(o[3]));
      hb.x = __half_as_ushort(__float2half(o[4]));
      hb.y = __half_as_ushort(__float2half(o[5]));
      hb.z = __half_as_ushort(__float2half(o[6]));
      hb.w = __half_as_ushort(__float2half(o[7]));
      *(ushort4*)&oh16[(size_t)node * 128 + c0] = ha;
      *(ushort4*)&oh16[(size_t)node * 128 + c0 + 4] = hb;
    }
  }
}

// ------------------------------ classifier ---------------------------------
__global__ __launch_bounds__(256) void classifier_kernel(const float4* __restrict__ h4,
                                                         const float* __restrict__ Wc,
                                                         const float* __restrict__ bc,
                                                         float* __restrict__ logits,
                                                         int n) {
  __shared__ float sW[2048];
  __shared__ float sb[16];
  int t = threadIdx.x;
#pragma unroll
  for (int i = 0; i < 8; ++i) sW[t + i * 256] = Wc[t + i * 256];
  if (t < 16) sb[t] = bc[t];
  __syncthreads();
  int node = blockIdx.x * 256 + t;
  if (node >= n) return;
  float acc[16];
#pragma unroll
  for (int o = 0; o < 16; ++o) acc[o] = sb[o];
  for (int c4 = 0; c4 < 32; ++c4) {
    float4 hv = h4[(unsigned)node * 32 + c4];
    const float* w = &sW[c4 * 64];
#pragma unroll
    for (int o = 0; o < 16; ++o) {
      acc[o] = fmaf(hv.x, w[o], acc[o]);
      acc[o] = fmaf(hv.y, w[16 + o], acc[o]);
      acc[o] = fmaf(hv.z, w[32 + o], acc[o]);
      acc[o] = fmaf(hv.w, w[48 + o], acc[o]);
    }
  }
#pragma unroll
  for (int q = 0; q < 4; ++q)
    *(float4*)&logits[(size_t)node * 16 + q * 4] =
        make_float4(acc[q * 4], acc[q * 4 + 1], acc[q * 4 + 2], acc[q * 4 + 3]);
}

// ---------------------------------------------------------------------------

extern "C" void kernel_launch(void* const* d_in, const int* in_sizes, int n_in,
                              void* d_out, int out_size, void* d_ws, size_t ws_size,
                              hipStream_t stream) {
  const float* x    = (const float*)d_in[0];
  const int*   ei   = (const int*)d_in[1];
  const float* Wl1  = (const float*)d_in[3];
  const float* Wr1  = (const float*)d_in[4];
  const float* att1 = (const float*)d_in[5];
  const float* b1   = (const float*)d_in[6];
  const float* Wl2  = (const float*)d_in[7];
  const float* Wr2  = (const float*)d_in[8];
  const float* att2 = (const float*)d_in[9];
  const float* b2   = (const float*)d_in[10];
  const float* Wc   = (const float*)d_in[11];
  const float* bc   = (const float*)d_in[12];

  const int N = in_sizes[0] / 128;
  const int E = in_sizes[1] / 2;

  float* outp   = (float*)d_out;
  float* logits = outp;                   // N*16 fp32
  float* hout   = outp + (size_t)N * 16;  // N*128 fp32 region
  // h1 (fp16) staged in the hout region (overwritten by fp32 h2 later)
  __half* h1f16 = (__half*)hout;

  char* ws = (char*)d_ws;
  __half* xlbuf = (__half*)ws;                ws += (size_t)N * 128 * 2;
  __half* xrbuf = (__half*)ws;                ws += (size_t)N * 128 * 2;
  unsigned short* WT1h = (unsigned short*)ws; ws += 256 * 128 * 2;
  unsigned short* WT1l = (unsigned short*)ws; ws += 256 * 128 * 2;
  unsigned short* WT2h = (unsigned short*)ws; ws += 256 * 128 * 2;
  unsigned short* WT2l = (unsigned short*)ws; ws += 256 * 128 * 2;
  int* cnt       = (int*)ws;                  ws += (size_t)N * 4;
  int* row_start = (int*)ws;                  ws += (size_t)(N + 1) * 4;
  int* wpos      = (int*)ws;                  ws += (size_t)N * 4;
  int* bsum      = (int*)ws;                  ws += 256 * 4;
  int* csr       = (int*)ws;                  ws += (size_t)(E + N + 16) * 4;

  const int* esrc = ei;
  const int* edst = ei + E;

  int gN = (N + 255) / 256, gE = (E + 255) / 256;
  int gAttn = (N + 3) / 4;
  int sliceSize = (N + 7) / 8;

  int nbx = (N + 127) / 128;
  int nGemm = nbx * 2;
  int groups = (NSCAT + 4) / 5;  // 231 -> covers >=128 chunks per slice
  int g2 = (nGemm + 3) / 4;
  if (g2 > groups) groups = g2;
  int gFused = groups * 9;

  // CSR build (self loops embedded: counts+1, csr[beg]=node)
  zero_i32<<<gN, 256, 0, stream>>>(cnt, N);
  convert_count<<<256 + gE, 256, 0, stream>>>(Wl1, Wr1, Wl2, Wr2,
                                              WT1h, WT1l, WT2h, WT2l,
                                              edst, cnt, E);
  scan_blk<<<gN, 256, 0, stream>>>(cnt, row_start, bsum, N);
  scan_bsum<<<1, 256, 0, stream>>>(bsum, gN, row_start, N);
  scan_add<<<gN, 256, 0, stream>>>(row_start, bsum, wpos, csr, N, E + N);

  // layer 1 GEMM (fp32 x, split inline) fused with CSR scatter
  gemm_mfma<IN_F32, 1><<<gFused, 256, 0, stream>>>(
      x, nullptr, WT1h, WT1l, xlbuf, xrbuf, N,
      esrc, edst, wpos, csr, E, sliceSize);
  gat_attn<<<gAttn, 256, 0, stream>>>(xlbuf, xrbuf, row_start, csr, att1, b1,
                                      nullptr, h1f16, N);

  // layer 2 (reads fp16 h1, splits inline; writes fp16 xl/xr)
  gemm_mfma<IN_F16, 0><<<dim3(nbx, 2), 256, 0, stream>>>(
      nullptr, h1f16, WT2h, WT2l, xlbuf, xrbuf, N,
      nullptr, nullptr, nullptr, nullptr, 0, 0);
  gat_attn<<<gAttn, 256, 0, stream>>>(xlbuf, xrbuf, row_start, csr, att2, b2,
                                      hout, nullptr, N);

  // classifier
  classifier_kernel<<<(N + 255) / 256, 256, 0, stream>>>((const float4*)hout, Wc, bc,
                                                         logits, N);
}

// Round 7
// 307.042 us; speedup vs baseline: 1.0939x; 1.0236x over previous
//
#include <hip/hip_runtime.h>
#include <hip/hip_fp16.h>

// ---------------------------------------------------------------------------
// GATv2 x2 + classifier. N=50000, E=800000, IN=128, HEADS=4, HID=32, OUT=16.
// R17: scatter's 8x edge re-scan eliminated via bucket pre-partition.
//      R16 counters: top-5 = fused gemm1+scatter at 60-66us, FETCH 51MB
//      (~25MB = dst re-read 8x, the price of slice<->XCD write binding).
//      The count pass (touches every edge anyway) now also bins edges into 8
//      per-slice buckets (LDS histogram -> one global cursor atomicAdd per
//      bucket -> contiguous ~1KB run writes). Fused scatter blocks read ONLY
//      their slice's bucket segment: 1x scan, no filtering, same XCD-bound
//      csr writes (structure unchanged -- only the loop body differs).
//      zero_i32 launch replaced by hipMemsetAsync(cnt+bucketCur).
//      KEPT (R16-verified): R10-form attn + separate classifier, fused
//      scatter+gemm1 grid structure, h1 fp16, setprio MFMA cluster.
// ---------------------------------------------------------------------------

#define LOG2E 1.4426950408889634f
#define AST 40  // LDS row stride in shorts (80B rows; fragment reads 2-way=free)

typedef short bf16x8 __attribute__((ext_vector_type(8)));
typedef float f32x4 __attribute__((ext_vector_type(4)));

__device__ __forceinline__ unsigned short f2bf(float f) {
  union { float f; unsigned u; } x; x.f = f;
  unsigned r = x.u + 0x7fffu + ((x.u >> 16) & 1u);
  return (unsigned short)(r >> 16);
}
__device__ __forceinline__ float bf2f(unsigned short h) {
  union { unsigned u; float f; } x; x.u = ((unsigned)h) << 16;
  return x.f;
}
__device__ __forceinline__ void split4(float4 v, ushort4& h, ushort4& l) {
  h.x = f2bf(v.x); l.x = f2bf(v.x - bf2f(h.x));
  h.y = f2bf(v.y); l.y = f2bf(v.y - bf2f(h.y));
  h.z = f2bf(v.z); l.z = f2bf(v.z - bf2f(h.z));
  h.w = f2bf(v.w); l.w = f2bf(v.w - bf2f(h.w));
}

// ------------------------------ CSR build ----------------------------------

// per-block scan of (cnt[i]+1)  (+1 = self loop slot)
__global__ __launch_bounds__(256) void scan_blk(const int* __restrict__ cnt,
                                                int* __restrict__ excl,
                                                int* __restrict__ bsum, int n) {
  __shared__ int s[256];
  int t = threadIdx.x, i = blockIdx.x * 256 + t;
  int v = (i < n) ? (cnt[i] + 1) : 0;
  s[t] = v;
  __syncthreads();
#pragma unroll
  for (int off = 1; off < 256; off <<= 1) {
    int u = (t >= off) ? s[t - off] : 0;
    __syncthreads();
    s[t] += u;
    __syncthreads();
  }
  if (i < n) excl[i] = s[t] - v;
  if (t == 255) bsum[blockIdx.x] = s[255];
}

__global__ __launch_bounds__(256) void scan_bsum(int* __restrict__ bsum, int nb,
                                                 int* __restrict__ row_start, int n) {
  __shared__ int s[256];
  int t = threadIdx.x;
  int v = (t < nb) ? bsum[t] : 0;
  s[t] = v;
  __syncthreads();
#pragma unroll
  for (int off = 1; off < 256; off <<= 1) {
    int u = (t >= off) ? s[t - off] : 0;
    __syncthreads();
    s[t] += u;
    __syncthreads();
  }
  if (t < nb) bsum[t] = s[t] - v;
  if (t == 255) row_start[n] = s[255];
}

// add block offsets; write self-loop entry; wpos starts past it; zero csr pad
__global__ __launch_bounds__(256) void scan_add(int* __restrict__ row_start,
                                                const int* __restrict__ bsum,
                                                int* __restrict__ wpos,
                                                int* __restrict__ csr,
                                                int n, int padBase) {
  int i = blockIdx.x * 256 + threadIdx.x;
  if (i < n) {
    int r = row_start[i] + bsum[blockIdx.x];
    row_start[i] = r;
    wpos[i] = r + 1;
    csr[r] = i;  // self loop first in each row
  }
  if (blockIdx.x == 0 && threadIdx.x < 16) csr[padBase + threadIdx.x] = 0;
}

// ------------- weight convert + degree count + slice bucketing -------------
// blocks 0..255: split-bf16 weight transpose (both layers)
// blocks 256.. : 1024 edges each: degree count + append (src,dst) to the
//                dst-slice bucket (LDS histogram -> 1 global cursor
//                atomicAdd per bucket -> contiguous run writes).
#define EPB 1024
__global__ __launch_bounds__(256) void convert_count(
    const float* __restrict__ Wl1, const float* __restrict__ Wr1,
    const float* __restrict__ Wl2, const float* __restrict__ Wr2,
    unsigned short* __restrict__ BT1h, unsigned short* __restrict__ BT1l,
    unsigned short* __restrict__ BT2h, unsigned short* __restrict__ BT2l,
    const int* __restrict__ esrc, const int* __restrict__ edst,
    int* __restrict__ cnt, int* __restrict__ bucketCur,
    int2* __restrict__ bucket, int E, int sliceSize, int cap) {
  int b = blockIdx.x;
  int t = threadIdx.x;
  if (b >= 256) {
    __shared__ int bcnt[8], bbase[8];
    if (t < 8) bcnt[t] = 0;
    __syncthreads();
    int base = (b - 256) * EPB;
    int sl[4], rk[4], dv[4], sv[4];
#pragma unroll
    for (int j = 0; j < 4; ++j) {
      int i = base + t + j * 256;
      bool v = (i < E);
      int d = v ? edst[i] : 0;
      sv[j] = v ? esrc[i] : 0;
      dv[j] = d;
      int s = d / sliceSize;  // 0..7
      sl[j] = v ? s : -1;
      if (v) {
        atomicAdd(&cnt[d], 1);
        rk[j] = atomicAdd(&bcnt[s], 1);
      }
    }
    __syncthreads();
    if (t < 8 && bcnt[t] > 0) bbase[t] = atomicAdd(&bucketCur[t], bcnt[t]);
    __syncthreads();
#pragma unroll
    for (int j = 0; j < 4; ++j) {
      if (sl[j] >= 0) {
        int pos = sl[j] * cap + bbase[sl[j]] + rk[j];
        bucket[pos] = make_int2(sv[j], dv[j]);
      }
    }
    return;
  }
  const float* Wl = (b < 128) ? Wl1 : Wl2;
  const float* Wr = (b < 128) ? Wr1 : Wr2;
  unsigned short* BTh = (b < 128) ? BT1h : BT2h;
  unsigned short* BTl = (b < 128) ? BT1l : BT2l;
  int idx = (b & 127) * 256 + t;  // 0..32767
  int col = idx >> 7, k = idx & 127;
  float v = (col < 128) ? Wl[k * 128 + col] : Wr[k * 128 + (col - 128)];
  unsigned short h = f2bf(v);
  BTh[idx] = h;
  BTl[idx] = f2bf(v - bf2f(h));
}

// ------------------------ MFMA GEMM (+fused scatter) -----------------------
// C[N x 256] = A[N x 128] @ W[128 x 256], split-bf16 3-term; C stored fp16.
// Block = 128 rows x 128 cols. 4 waves, each 64x64 (16 acc tiles).
// FUSE=1: grid also carries scatter blocks (5 of every 9). Scatter slice is
// the REAL blockIdx&7 (== XCD on round-robin dispatch) so each csr slice is
// written by exactly one XCD's L2; chunk = rank among same-slice blocks.
// Scatter reads ONLY its slice's pre-bucketed edges (1x scan, no filter).
enum { IN_F32 = 0, IN_F16 = 1 };
#define NSCAT 1152
#define NCHUNK 128
template <int MODE, int FUSE>
__global__ __launch_bounds__(256) void gemm_mfma(
    const float* __restrict__ Af, const __half* __restrict__ Af16,
    const unsigned short* __restrict__ BTh, const unsigned short* __restrict__ BTl,
    __half* __restrict__ Cl, __half* __restrict__ Cr, int nrows,
    const int2* __restrict__ bucket, const int* __restrict__ bucketCur,
    int* __restrict__ wpos, int* __restrict__ csr, int cap) {
  __shared__ __align__(16) unsigned short smem[4 * 128 * AST];
  int tid = threadIdx.x;
  int bx, by;
  if (FUSE) {
    int g = blockIdx.x / 9, r = blockIdx.x - g * 9;
    if (r < 5) {  // ---- scatter role ----
      int sid = g * 5 + r;
      if (sid < NSCAT) {
        int slice = blockIdx.x & 7;  // == XCD (round-robin dispatch)
        // rank among scatter blocks with the same slice, ordered by g:
        // block (g',r') has slice (g'+r')&7; per g' at most one r'<5 matches.
        int chunk = (g >> 3) * 5;
        for (int gp = g & ~7; gp < g; ++gp)
          chunk += (((slice - gp) & 7) < 5) ? 1 : 0;
        if (chunk < NCHUNK) {
          int cntS = bucketCur[slice];
          int per = (cntS + NCHUNK - 1) / NCHUNK;
          int b0 = chunk * per;
          int ee = min(b0 + per, cntS);
          const int2* bk = bucket + (size_t)slice * cap;
          int i = b0 + tid;
          // 2x-batched: 2 independent bucket loads in flight
          for (; i + 256 < ee; i += 512) {
            int2 e0 = bk[i];
            int2 e1 = bk[i + 256];
            int p0 = atomicAdd(&wpos[e0.y], 1); csr[p0] = e0.x;
            int p1 = atomicAdd(&wpos[e1.y], 1); csr[p1] = e1.x;
          }
          for (; i < ee; i += 256) {
            int2 e = bk[i];
            int p = atomicAdd(&wpos[e.y], 1); csr[p] = e.x;
          }
        }
      }
      return;
    }
    int gid = g * 4 + (r - 5);  // ---- gemm role ----
    int nbx = (nrows + 127) >> 7;
    if (gid >= nbx * 2) return;
    bx = gid >> 1;
    by = gid & 1;
  } else {
    bx = blockIdx.x;
    by = blockIdx.y;
  }

  unsigned short* sAh = smem;
  unsigned short* sAl = smem + 5120;
  unsigned short* sBh = smem + 10240;
  unsigned short* sBl = smem + 15360;

  int wave = tid >> 6, lane = tid & 63;
  int rowBase = bx * 128;
  int colBase = by * 128;
  int rowHalf = (wave >> 1) * 64;
  int colHalf = (wave & 1) * 64;
  int l15 = lane & 15, quad = lane >> 4;

  f32x4 acc[4][4];
#pragma unroll
  for (int m = 0; m < 4; ++m)
#pragma unroll
    for (int n = 0; n < 4; ++n) acc[m][n] = (f32x4){0.f, 0.f, 0.f, 0.f};

  for (int kc = 0; kc < 4; ++kc) {
    // stage A: 128 rows x 32 k (hi+lo); idx 0..511, 8 k-elems each
#pragma unroll
    for (int i = 0; i < 2; ++i) {
      int idx = tid + i * 256;
      int row = idx >> 2, seg = idx & 3;
      int gr = rowBase + row;
      float4 v0 = make_float4(0.f, 0.f, 0.f, 0.f), v1 = v0;
      if (MODE == IN_F32) {
        if (gr < nrows) {
          v0 = *(const float4*)&Af[(size_t)gr * 128 + kc * 32 + seg * 8];
          v1 = *(const float4*)&Af[(size_t)gr * 128 + kc * 32 + seg * 8 + 4];
        }
      } else {
        if (gr < nrows) {
          uint4 raw = *(const uint4*)&Af16[(size_t)gr * 128 + kc * 32 + seg * 8];
          const __half* hp = (const __half*)&raw;
          v0 = make_float4(__half2float(hp[0]), __half2float(hp[1]),
                           __half2float(hp[2]), __half2float(hp[3]));
          v1 = make_float4(__half2float(hp[4]), __half2float(hp[5]),
                           __half2float(hp[6]), __half2float(hp[7]));
        }
      }
      ushort4 h0, l0, h1, l1;
      split4(v0, h0, l0);
      split4(v1, h1, l1);
      *(ushort4*)&sAh[row * AST + seg * 8] = h0;
      *(ushort4*)&sAh[row * AST + seg * 8 + 4] = h1;
      *(ushort4*)&sAl[row * AST + seg * 8] = l0;
      *(ushort4*)&sAl[row * AST + seg * 8 + 4] = l1;
    }
    // stage B: 128 cols x 32 k (hi+lo); idx 0..511
#pragma unroll
    for (int i = 0; i < 2; ++i) {
      int idx = tid + i * 256;
      int col = idx >> 2, seg = idx & 3;
      *(uint4*)&sBh[col * AST + seg * 8] =
          *(const uint4*)&BTh[(size_t)(colBase + col) * 128 + kc * 32 + seg * 8];
      *(uint4*)&sBl[col * AST + seg * 8] =
          *(const uint4*)&BTl[(size_t)(colBase + col) * 128 + kc * 32 + seg * 8];
    }
    __syncthreads();

    bf16x8 afh[4], afl[4], bfh[4], bfl[4];
#pragma unroll
    for (int m = 0; m < 4; ++m) {
      int r = rowHalf + m * 16 + l15;
      afh[m] = *(const bf16x8*)&sAh[r * AST + quad * 8];
      afl[m] = *(const bf16x8*)&sAl[r * AST + quad * 8];
    }
#pragma unroll
    for (int n = 0; n < 4; ++n) {
      int cc = colHalf + n * 16 + l15;
      bfh[n] = *(const bf16x8*)&sBh[cc * AST + quad * 8];
      bfl[n] = *(const bf16x8*)&sBl[cc * AST + quad * 8];
    }
    __builtin_amdgcn_s_setprio(1);
#pragma unroll
    for (int m = 0; m < 4; ++m)
#pragma unroll
      for (int n = 0; n < 4; ++n) {
        acc[m][n] = __builtin_amdgcn_mfma_f32_16x16x32_bf16(afh[m], bfh[n], acc[m][n], 0, 0, 0);
        acc[m][n] = __builtin_amdgcn_mfma_f32_16x16x32_bf16(afh[m], bfl[n], acc[m][n], 0, 0, 0);
        acc[m][n] = __builtin_amdgcn_mfma_f32_16x16x32_bf16(afl[m], bfh[n], acc[m][n], 0, 0, 0);
      }
    __builtin_amdgcn_s_setprio(0);
    __syncthreads();
  }

  __half* __restrict__ C = (by == 0) ? Cl : Cr;
#pragma unroll
  for (int m = 0; m < 4; ++m)
#pragma unroll
    for (int r = 0; r < 4; ++r) {
      int grow = rowBase + rowHalf + m * 16 + quad * 4 + r;
      if (grow < nrows) {
#pragma unroll
        for (int n = 0; n < 4; ++n)
          C[(size_t)grow * 128 + colHalf + n * 16 + l15] = __float2half(acc[m][n][r]);
      }
    }
}

// ------------------------------ attention ----------------------------------
// R10-proven form. One wave per node; 16 lanes/edge (8 ch/lane, one b128
// fp16 load); 4 edge-slots/wave. Main loop 16 edges/iter, tail 4 edges/iter.
// Self loop lives in csr (csr[beg] = node). Outputs fp32 and/or fp16.
__global__ __launch_bounds__(256) void gat_attn(const __half* __restrict__ xl,
                                                const __half* __restrict__ xr,
                                                const int* __restrict__ row_start,
                                                const int* __restrict__ csr,
                                                const float* __restrict__ att,
                                                const float* __restrict__ bias,
                                                float* __restrict__ ofp,
                                                __half* __restrict__ oh16,
                                                int n_nodes) {
  int node = blockIdx.x * 4 + (threadIdx.x >> 6);
  if (node >= n_nodes) return;
  int lane = threadIdx.x & 63;
  int slot = lane >> 4;
  int l15 = lane & 15;
  int c0 = l15 * 8;

  // xr row (fp16 -> fp32)
  float fxr[8];
  {
    uint4 raw = *(const uint4*)&xr[(size_t)node * 128 + c0];
    const __half* hp = (const __half*)&raw;
#pragma unroll
    for (int k = 0; k < 8; ++k) fxr[k] = __half2float(hp[k]);
  }
  // att row, pre-scaled: a06 = 0.6*log2e*a, a04 = 0.4*log2e*a
  float a06[8], a04[8];
  {
    float4 a0 = *(const float4*)&att[c0];
    float4 a1 = *(const float4*)&att[c0 + 4];
    float av[8] = {a0.x, a0.y, a0.z, a0.w, a1.x, a1.y, a1.z, a1.w};
    const float C06 = 0.6f * LOG2E, C04 = 0.4f * LOG2E;
#pragma unroll
    for (int k = 0; k < 8; ++k) { a06[k] = av[k] * C06; a04[k] = av[k] * C04; }
  }

  float acc[8];
#pragma unroll
  for (int k = 0; k < 8; ++k) acc[k] = 0.f;
  float lsum = 0.f;

#define EDGE_BODY(SRC, PVALID)                                                 \
  {                                                                            \
    uint4 raw = *(const uint4*)&xl[(size_t)(unsigned)(SRC)*128 + c0];          \
    const __half* hp = (const __half*)&raw;                                    \
    float e = 0.f;                                                             \
    _Pragma("unroll") for (int k = 0; k < 8; ++k) {                            \
      float t = __half2float(hp[k]) + fxr[k];                                  \
      e = fmaf(a06[k], t, e);                                                  \
      e = fmaf(a04[k], fabsf(t), e);                                           \
    }                                                                          \
    e += __shfl_xor(e, 1);                                                     \
    e += __shfl_xor(e, 2);                                                     \
    float p = (PVALID) ? __builtin_amdgcn_exp2f(e) : 0.f;                      \
    lsum += p;                                                                 \
    _Pragma("unroll") for (int k = 0; k < 8; ++k)                              \
        acc[k] = fmaf(p, __half2float(hp[k]), acc[k]);                         \
  }

  int beg = row_start[node], end = row_start[node + 1];
  int deg = end - beg;  // includes self
  int fullEnd = beg + (deg & ~15);

  for (int base = beg; base < fullEnd; base += 16) {
    int b0 = base + 4 * slot;
    int s0 = csr[b0], s1 = csr[b0 + 1], s2 = csr[b0 + 2], s3 = csr[b0 + 3];
    EDGE_BODY(s0, true);
    EDGE_BODY(s1, true);
    EDGE_BODY(s2, true);
    EDGE_BODY(s3, true);
  }
  for (int base = fullEnd; base < end; base += 4) {  // csr padded by 16
    int idx = base + slot;
    int src = csr[idx];
    EDGE_BODY(src, idx < end);
  }
#undef EDGE_BODY

  // merge the 4 slots (same channels live in lanes with equal l15)
  lsum += __shfl_xor(lsum, 16);
  lsum += __shfl_xor(lsum, 32);
#pragma unroll
  for (int k = 0; k < 8; ++k) {
    acc[k] += __shfl_xor(acc[k], 16);
    acc[k] += __shfl_xor(acc[k], 32);
  }

  if (slot == 0) {
    float4 b0v = *(const float4*)&bias[c0];
    float4 b1v = *(const float4*)&bias[c0 + 4];
    float bv[8] = {b0v.x, b0v.y, b0v.z, b0v.w, b1v.x, b1v.y, b1v.z, b1v.w};
    float inv = 1.f / (lsum + 1e-16f);
    float o[8];
#pragma unroll
    for (int k = 0; k < 8; ++k) {
      float v = fmaf(acc[k], inv, bv[k]);
      o[k] = fmaf(0.495f, fabsf(v), 0.505f * v);  // leaky 0.01
    }
    if (ofp) {
      *(float4*)&ofp[(size_t)node * 128 + c0] = make_float4(o[0], o[1], o[2], o[3]);
      *(float4*)&ofp[(size_t)node * 128 + c0 + 4] = make_float4(o[4], o[5], o[6], o[7]);
    }
    if (oh16) {
      ushort4 ha, hb;
      ha.x = __half_as_ushort(__float2half(o[0]));
      ha.y = __half_as_ushort(__float2half(o[1]));
      ha.z = __half_as_ushort(__float2half(o[2]));
      ha.w = __half_as_ushort(__float2half(o[3]));
      hb.x = __half_as_ushort(__float2half(o[4]));
      hb.y = __half_as_ushort(__float2half(o[5]));
      hb.z = __half_as_ushort(__float2half(o[6]));
      hb.w = __half_as_ushort(__float2half(o[7]));
      *(ushort4*)&oh16[(size_t)node * 128 + c0] = ha;
      *(ushort4*)&oh16[(size_t)node * 128 + c0 + 4] = hb;
    }
  }
}

// ------------------------------ classifier ---------------------------------
__global__ __launch_bounds__(256) void classifier_kernel(const float4* __restrict__ h4,
                                                         const float* __restrict__ Wc,
                                                         const float* __restrict__ bc,
                                                         float* __restrict__ logits,
                                                         int n) {
  __shared__ float sW[2048];
  __shared__ float sb[16];
  int t = threadIdx.x;
#pragma unroll
  for (int i = 0; i < 8; ++i) sW[t + i * 256] = Wc[t + i * 256];
  if (t < 16) sb[t] = bc[t];
  __syncthreads();
  int node = blockIdx.x * 256 + t;
  if (node >= n) return;
  float acc[16];
#pragma unroll
  for (int o = 0; o < 16; ++o) acc[o] = sb[o];
  for (int c4 = 0; c4 < 32; ++c4) {
    float4 hv = h4[(unsigned)node * 32 + c4];
    const float* w = &sW[c4 * 64];
#pragma unroll
    for (int o = 0; o < 16; ++o) {
      acc[o] = fmaf(hv.x, w[o], acc[o]);
      acc[o] = fmaf(hv.y, w[16 + o], acc[o]);
      acc[o] = fmaf(hv.z, w[32 + o], acc[o]);
      acc[o] = fmaf(hv.w, w[48 + o], acc[o]);
    }
  }
#pragma unroll
  for (int q = 0; q < 4; ++q)
    *(float4*)&logits[(size_t)node * 16 + q * 4] =
        make_float4(acc[q * 4], acc[q * 4 + 1], acc[q * 4 + 2], acc[q * 4 + 3]);
}

// ---------------------------------------------------------------------------

extern "C" void kernel_launch(void* const* d_in, const int* in_sizes, int n_in,
                              void* d_out, int out_size, void* d_ws, size_t ws_size,
                              hipStream_t stream) {
  const float* x    = (const float*)d_in[0];
  const int*   ei   = (const int*)d_in[1];
  const float* Wl1  = (const float*)d_in[3];
  const float* Wr1  = (const float*)d_in[4];
  const float* att1 = (const float*)d_in[5];
  const float* b1   = (const float*)d_in[6];
  const float* Wl2  = (const float*)d_in[7];
  const float* Wr2  = (const float*)d_in[8];
  const float* att2 = (const float*)d_in[9];
  const float* b2   = (const float*)d_in[10];
  const float* Wc   = (const float*)d_in[11];
  const float* bc   = (const float*)d_in[12];

  const int N = in_sizes[0] / 128;
  const int E = in_sizes[1] / 2;

  float* outp   = (float*)d_out;
  float* logits = outp;                   // N*16 fp32
  float* hout   = outp + (size_t)N * 16;  // N*128 fp32 region
  // h1 (fp16) staged in the hout region (overwritten by fp32 h2 later)
  __half* h1f16 = (__half*)hout;

  const int cap = E / 8 + 16384;  // per-slice bucket capacity (27+ sigma)

  char* ws = (char*)d_ws;
  __half* xlbuf = (__half*)ws;                ws += (size_t)N * 128 * 2;
  __half* xrbuf = (__half*)ws;                ws += (size_t)N * 128 * 2;
  unsigned short* WT1h = (unsigned short*)ws; ws += 256 * 128 * 2;
  unsigned short* WT1l = (unsigned short*)ws; ws += 256 * 128 * 2;
  unsigned short* WT2h = (unsigned short*)ws; ws += 256 * 128 * 2;
  unsigned short* WT2l = (unsigned short*)ws; ws += 256 * 128 * 2;
  int* cnt       = (int*)ws;                  ws += (size_t)N * 4;
  int* bucketCur = (int*)ws;                  ws += 8 * 4;           // after cnt (one memset)
  int* wpos      = (int*)ws;                  ws += (size_t)N * 4;
  int* bsum      = (int*)ws;                  ws += 256 * 4;
  int2* bucket   = (int2*)ws;                 ws += (size_t)8 * cap * 8;
  int* row_start = (int*)ws;                  ws += (size_t)(N + 1) * 4;
  int* csr       = (int*)ws;                  ws += (size_t)(E + N + 16) * 4;

  const int* esrc = ei;
  const int* edst = ei + E;

  int gN = (N + 255) / 256;
  int gAttn = (N + 3) / 4;
  int sliceSize = (N + 7) / 8;

  int nbx = (N + 127) / 128;
  int nGemm = nbx * 2;
  int groups = (NSCAT + 4) / 5;  // 231 -> covers >=128 chunks per slice
  int g2 = (nGemm + 3) / 4;
  if (g2 > groups) groups = g2;
  int gFused = groups * 9;

  // CSR build (self loops embedded: counts+1, csr[beg]=node)
  hipMemsetAsync(cnt, 0, (size_t)(N + 8) * 4, stream);  // cnt + bucketCur
  convert_count<<<256 + (E + EPB - 1) / EPB, 256, 0, stream>>>(
      Wl1, Wr1, Wl2, Wr2, WT1h, WT1l, WT2h, WT2l,
      esrc, edst, cnt, bucketCur, bucket, E, sliceSize, cap);
  scan_blk<<<gN, 256, 0, stream>>>(cnt, row_start, bsum, N);
  scan_bsum<<<1, 256, 0, stream>>>(bsum, gN, row_start, N);
  scan_add<<<gN, 256, 0, stream>>>(row_start, bsum, wpos, csr, N, E + N);

  // layer 1 GEMM (fp32 x, split inline) fused with bucketed CSR scatter
  gemm_mfma<IN_F32, 1><<<gFused, 256, 0, stream>>>(
      x, nullptr, WT1h, WT1l, xlbuf, xrbuf, N,
      bucket, bucketCur, wpos, csr, cap);
  gat_attn<<<gAttn, 256, 0, stream>>>(xlbuf, xrbuf, row_start, csr, att1, b1,
                                      nullptr, h1f16, N);

  // layer 2 (reads fp16 h1, splits inline; writes fp16 xl/xr)
  gemm_mfma<IN_F16, 0><<<dim3(nbx, 2), 256, 0, stream>>>(
      nullptr, h1f16, WT2h, WT2l, xlbuf, xrbuf, N,
      nullptr, nullptr, nullptr, nullptr, 0);
  gat_attn<<<gAttn, 256, 0, stream>>>(xlbuf, xrbuf, row_start, csr, att2, b2,
                                      hout, nullptr, N);

  // classifier
  classifier_kernel<<<(N + 255) / 256, 256, 0, stream>>>((const float4*)hout, Wc, bc,
                                                         logits, N);
}